// Round 2
// baseline (1059.812 us; speedup 1.0000x reference)
//
#include <hip/hip_runtime.h>

#define N1 4096
#define N2 2048
#define PD 256
#define DZ 128
#define PD2 258
#define FD 772

// lmFT[c][r] = lm_feature[r][c], c in [0,258), r in [0,4096)
__global__ void prep_lmFT(const float* __restrict__ lmX, const float* __restrict__ lmY,
                          float* __restrict__ lmFT) {
    int idx = blockIdx.x * blockDim.x + threadIdx.x;
    if (idx >= PD2 * N1) return;
    int c = idx >> 12;        // /4096
    int r = idx & (N1 - 1);   // %4096
    float v = (c < PD) ? lmX[r * PD + c] : lmY[r * 2 + (c - PD)];
    lmFT[idx] = v;
}

// delay_score / rou0 / rou1
__global__ void prep_delay(const float* __restrict__ lm_delay, const float* __restrict__ tg_delay,
                           const float* __restrict__ g1, const float* __restrict__ g2,
                           const float* __restrict__ g3, const float* __restrict__ al,
                           const float* __restrict__ be,
                           float* __restrict__ dscore, float* __restrict__ rou0,
                           float* __restrict__ rou1) {
    float a = al[0], b = be[0];
    int i = blockIdx.x * blockDim.x + threadIdx.x;
    if (i < N1) dscore[i] = __expf(-g1[0] * (a * lm_delay[i] + b));
    if (i < N2) {
        float t = a * tg_delay[i] + b;
        rou0[i] = __expf(-g2[0] * t);
        rou1[i] = __expf(-g3[0] * t);
    }
}

__global__ __launch_bounds__(256) void sum_reduce(const float* __restrict__ in, float* __restrict__ out, int n) {
    __shared__ float red[256];
    int tid = threadIdx.x;
    float s = 0.f;
    for (int i = tid; i < n; i += 256) s += in[i];
    red[tid] = s; __syncthreads();
    for (int o = 128; o > 0; o >>= 1) { if (tid < o) red[tid] += red[tid + o]; __syncthreads(); }
    if (tid == 0) out[0] = red[0];
}

// per-column: router0[c] = mean_i lmF[i][c]; routerp0[c] = (dscore·lmF[:,c] + router0[c]) / (1+sumdelay+eps)
__global__ __launch_bounds__(256) void router_kernel(const float* __restrict__ lmFT,
                                                     const float* __restrict__ dscore,
                                                     const float* __restrict__ scal,
                                                     float* __restrict__ router0,
                                                     float* __restrict__ routerp0) {
    int c = blockIdx.x;
    const float* rowp = lmFT + (size_t)c * N1;
    __shared__ float r1[256], r2[256];
    int tid = threadIdx.x;
    float s1 = 0.f, s2 = 0.f;
    for (int i = tid; i < N1; i += 256) {
        float v = rowp[i];
        s1 += v;
        s2 += dscore[i] * v;
    }
    r1[tid] = s1; r2[tid] = s2; __syncthreads();
    for (int o = 128; o > 0; o >>= 1) {
        if (tid < o) { r1[tid] += r1[tid + o]; r2[tid] += r2[tid + o]; }
        __syncthreads();
    }
    if (tid == 0) {
        float r0 = r1[0] / (float)N1;
        router0[c] = r0;
        routerp0[c] = (r2[0] + r0) / (1.f + scal[0] + 1e-12f);
    }
}

// ---------------------------------------------------------------- generic GEMM
// out[M,N] = scale * (X[M,K] @ W[N,K]^T + bias[N])
__global__ __launch_bounds__(256) void gemm_xt(const float* __restrict__ X,
                                               const float* __restrict__ W,
                                               const float* __restrict__ bias,
                                               float* __restrict__ out,
                                               int M, int N, int K, float scale) {
    __shared__ float sX[16][68];
    __shared__ float sW[16][68];
    const int tid = threadIdx.x;
    const int tx = tid & 15, ty = tid >> 4;
    const int row0 = blockIdx.y * 64, col0 = blockIdx.x * 64;
    float acc[4][4] = {};
    for (int k0 = 0; k0 < K; k0 += 16) {
#pragma unroll
        for (int l = 0; l < 4; ++l) {
            int idx = l * 256 + tid;
            int r = idx >> 4, c = idx & 15;
            int gc = k0 + c;
            int gr = row0 + r;
            sX[c][r] = (gr < M && gc < K) ? X[(size_t)gr * K + gc] : 0.f;
            int wr = col0 + r;
            sW[c][r] = (wr < N && gc < K) ? W[(size_t)wr * K + gc] : 0.f;
        }
        __syncthreads();
#pragma unroll
        for (int kk = 0; kk < 16; ++kk) {
            float a[4], b[4];
#pragma unroll
            for (int i = 0; i < 4; ++i) a[i] = sX[kk][ty * 4 + i];
#pragma unroll
            for (int j = 0; j < 4; ++j) b[j] = sW[kk][tx * 4 + j];
#pragma unroll
            for (int i = 0; i < 4; ++i)
#pragma unroll
                for (int j = 0; j < 4; ++j) acc[i][j] += a[i] * b[j];
        }
        __syncthreads();
    }
#pragma unroll
    for (int i = 0; i < 4; ++i) {
        int r = row0 + ty * 4 + i;
        if (r >= M) continue;
#pragma unroll
        for (int j = 0; j < 4; ++j) {
            int c = col0 + tx * 4 + j;
            if (c >= N) continue;
            float b = bias ? bias[c] : 0.f;
            out[(size_t)r * N + c] = scale * (acc[i][j] + b);
        }
    }
}

// ---------------------------------------------------------------- softmax kernels
// attention1: scores -> attr = exp(softmax(scores)), attr_sum per row
__global__ __launch_bounds__(256) void softmax_attr(float* __restrict__ scores,
                                                    float* __restrict__ attr_sum, int N) {
    int row = blockIdx.x;
    float* s = scores + (size_t)row * N;
    __shared__ float red[256];
    int tid = threadIdx.x;
    float m = -1e30f;
    for (int i = tid; i < N; i += 256) m = fmaxf(m, s[i]);
    red[tid] = m; __syncthreads();
    for (int o = 128; o > 0; o >>= 1) { if (tid < o) red[tid] = fmaxf(red[tid], red[tid + o]); __syncthreads(); }
    m = red[0]; __syncthreads();
    float z = 0.f;
    for (int i = tid; i < N; i += 256) z += __expf(s[i] - m);
    red[tid] = z; __syncthreads();
    for (int o = 128; o > 0; o >>= 1) { if (tid < o) red[tid] += red[tid + o]; __syncthreads(); }
    float invZ = 1.f / red[0]; __syncthreads();
    float asum = 0.f;
    for (int i = tid; i < N; i += 256) {
        float p = __expf(s[i] - m) * invZ;
        float a = __expf(p);
        s[i] = a;
        asum += a;
    }
    red[tid] = asum; __syncthreads();
    for (int o = 128; o > 0; o >>= 1) { if (tid < o) red[tid] += red[tid + o]; __syncthreads(); }
    if (tid == 0) attr_sum[row] = red[0];
}

// attention2 fused: y_pred[row] = softmax(scores[row]) @ v2
__global__ __launch_bounds__(256) void softmax_pv(const float* __restrict__ scores,
                                                  const float* __restrict__ v2,
                                                  float* __restrict__ yout, int N) {
    int row = blockIdx.x;
    const float* s = scores + (size_t)row * N;
    __shared__ float red[256];
    int tid = threadIdx.x;
    float m = -1e30f;
    for (int i = tid; i < N; i += 256) m = fmaxf(m, s[i]);
    red[tid] = m; __syncthreads();
    for (int o = 128; o > 0; o >>= 1) { if (tid < o) red[tid] = fmaxf(red[tid], red[tid + o]); __syncthreads(); }
    m = red[0]; __syncthreads();
    float z = 0.f, y0 = 0.f, y1 = 0.f;
    for (int i = tid; i < N; i += 256) {
        float e = __expf(s[i] - m);
        z += e;
        y0 += e * v2[2 * i];
        y1 += e * v2[2 * i + 1];
    }
    red[tid] = z; __syncthreads();
    for (int o = 128; o > 0; o >>= 1) { if (tid < o) red[tid] += red[tid + o]; __syncthreads(); }
    z = red[0]; __syncthreads();
    red[tid] = y0; __syncthreads();
    for (int o = 128; o > 0; o >>= 1) { if (tid < o) red[tid] += red[tid + o]; __syncthreads(); }
    y0 = red[0]; __syncthreads();
    red[tid] = y1; __syncthreads();
    for (int o = 128; o > 0; o >>= 1) { if (tid < o) red[tid] += red[tid + o]; __syncthreads(); }
    y1 = red[0];
    if (tid == 0) {
        float invz = 1.f / z;
        yout[2 * row] = y0 * invz;
        yout[2 * row + 1] = y1 * invz;
    }
}

// ---------------------------------------------------------------- elementwise fixups
// tgp0 (currently holding attr@lmF) -> (AP + tgF0 + rou0*router0) / (1+attr_sum+rou0+eps)
__global__ void fix_tgp0(float* __restrict__ tgp0, const float* __restrict__ tgX,
                         const float* __restrict__ rou0, const float* __restrict__ router0,
                         const float* __restrict__ attr_sum) {
    int idx = blockIdx.x * blockDim.x + threadIdx.x;
    if (idx >= N2 * PD2) return;
    int j = idx / PD2, c = idx % PD2;
    float t0 = (c < PD) ? tgX[j * PD + c] : 0.f;
    float deg = 1.f + attr_sum[j] + rou0[j];
    tgp0[idx] = (tgp0[idx] + t0 + rou0[j] * router0[c]) / (deg + 1e-12f);
}

// tgp1 = (tf1 + rou1[j]*router1[c]) / (1 + rou1[j] + eps)
__global__ void make_tgp1(const float* __restrict__ tf1, const float* __restrict__ rou1,
                          const float* __restrict__ router1, float* __restrict__ tgp1) {
    int idx = blockIdx.x * blockDim.x + threadIdx.x;
    if (idx >= N2 * PD2) return;
    int j = idx / PD2, c = idx % PD2;
    tgp1[idx] = (tf1[idx] + rou1[j] * router1[c]) / (1.f + rou1[j] + 1e-12f);
}

// final_tg_feature = [tgX | tf1 | tf2] written directly into out+N2*2 (f32)
__global__ void build_final(const float* __restrict__ tgX, const float* __restrict__ tf1,
                            const float* __restrict__ tf2, float* __restrict__ outF) {
    int idx = blockIdx.x * blockDim.x + threadIdx.x;
    if (idx >= N2 * FD) return;
    int j = idx / FD, c = idx % FD;
    float v;
    if (c < PD) v = tgX[j * PD + c];
    else if (c < PD + PD2) v = tf1[j * PD2 + (c - PD)];
    else v = tf2[j * PD2 + (c - PD - PD2)];
    outF[idx] = v;
}

// v2 = lm_Y @ pv_w^T + pv_b  (tiny)
__global__ void make_v2(const float* __restrict__ lmY, const float* __restrict__ pvw,
                        const float* __restrict__ pvb, float* __restrict__ v2) {
    int i = blockIdx.x * blockDim.x + threadIdx.x;
    if (i >= N1) return;
    float y0 = lmY[2 * i], y1 = lmY[2 * i + 1];
    v2[2 * i]     = pvw[0] * y0 + pvw[1] * y1 + pvb[0];
    v2[2 * i + 1] = pvw[2] * y0 + pvw[3] * y1 + pvb[1];
}

// ---------------------------------------------------------------- launch
extern "C" void kernel_launch(void* const* d_in, const int* in_sizes, int n_in,
                              void* d_out, int out_size, void* d_ws, size_t ws_size,
                              hipStream_t stream) {
    const float* lm_X = (const float*)d_in[0];
    const float* lm_Y = (const float*)d_in[1];
    const float* tg_X = (const float*)d_in[2];
    // d_in[3] = tg_Y (unused by reference)
    const float* lm_delay = (const float*)d_in[4];
    const float* tg_delay = (const float*)d_in[5];
    const float* aq_w = (const float*)d_in[6];
    const float* aq_b = (const float*)d_in[7];
    const float* ak_w = (const float*)d_in[8];
    const float* ak_b = (const float*)d_in[9];
    const float* w1_w = (const float*)d_in[10];
    const float* w1_b = (const float*)d_in[11];
    const float* w2_w = (const float*)d_in[12];
    const float* w2_b = (const float*)d_in[13];
    const float* pq_w = (const float*)d_in[14];
    const float* pq_b = (const float*)d_in[15];
    const float* pk_w = (const float*)d_in[16];
    const float* pk_b = (const float*)d_in[17];
    const float* pv_w = (const float*)d_in[18];
    const float* pv_b = (const float*)d_in[19];
    const float* g1 = (const float*)d_in[20];
    const float* g2 = (const float*)d_in[21];
    const float* g3 = (const float*)d_in[22];
    const float* al = (const float*)d_in[23];
    const float* be = (const float*)d_in[24];

    float* out = (float*)d_out;              // [N2*2 y_pred | N2*FD final features]
    float* outF = out + (size_t)N2 * 2;

    // ---- workspace layout (f32 buffers, 256B aligned)
    char* base = (char*)d_ws;
    size_t off = 0;
    auto alloc = [&](size_t nfloats) -> float* {
        float* p = (float*)(base + off);
        off += ((nfloats * sizeof(float)) + 255) / 256 * 256;
        return p;
    };
    float* scores   = alloc((size_t)N2 * N1);   // reused for both attentions
    float* lmFT     = alloc((size_t)PD2 * N1);  // lm_feature transposed [258][4096]
    float* qb       = alloc((size_t)N2 * DZ);
    float* kb       = alloc((size_t)N1 * DZ);
    float* q2b      = alloc((size_t)N2 * DZ);
    float* k2b      = alloc((size_t)N1 * DZ);
    float* v2b      = alloc((size_t)N1 * 2);
    float* tgp0     = alloc((size_t)N2 * PD2);
    float* tf1      = alloc((size_t)N2 * PD2);
    float* tgp1     = alloc((size_t)N2 * PD2);
    float* tf2      = alloc((size_t)N2 * PD2);
    float* router0  = alloc(PD2);
    float* routerp0 = alloc(PD2);
    float* router1  = alloc(PD2);
    float* dscore   = alloc(N1);
    float* rou0     = alloc(N2);
    float* rou1     = alloc(N2);
    float* attr_sum = alloc(N2);
    float* scal     = alloc(8);

    const float INV_TEMP = 0.08838834764831845f; // 1/sqrt(128)

    auto gemm = [&](const float* X, const float* W, const float* bias, float* o,
                    int M, int N, int K, float scale) {
        dim3 g((N + 63) / 64, (M + 63) / 64);
        hipLaunchKernelGGL(gemm_xt, g, dim3(256), 0, stream, X, W, bias, o, M, N, K, scale);
    };

    // ---- stage 0: small prep
    hipLaunchKernelGGL(prep_lmFT, dim3((PD2 * N1 + 255) / 256), dim3(256), 0, stream, lm_X, lm_Y, lmFT);
    hipLaunchKernelGGL(prep_delay, dim3((N1 + 255) / 256), dim3(256), 0, stream,
                       lm_delay, tg_delay, g1, g2, g3, al, be, dscore, rou0, rou1);
    hipLaunchKernelGGL(sum_reduce, dim3(1), dim3(256), 0, stream, dscore, scal, N1);
    hipLaunchKernelGGL(router_kernel, dim3(PD2), dim3(256), 0, stream, lmFT, dscore, scal, router0, routerp0);

    // ---- attention 1
    gemm(lm_X, ak_w, ak_b, kb, N1, DZ, PD, 1.f);
    gemm(tg_X, aq_w, aq_b, qb, N2, DZ, PD, INV_TEMP);
    gemm(qb, kb, nullptr, scores, N2, N1, DZ, 1.f);
    hipLaunchKernelGGL(softmax_attr, dim3(N2), dim3(256), 0, stream, scores, attr_sum, N1);

    // ---- propagation 0
    gemm(scores, lmFT, nullptr, tgp0, N2, PD2, N1, 1.f);   // attr @ lm_feature
    hipLaunchKernelGGL(fix_tgp0, dim3((N2 * PD2 + 255) / 256), dim3(256), 0, stream,
                       tgp0, tg_X, rou0, router0, attr_sum);

    // ---- layer 1
    gemm(tgp0, w1_w, w1_b, tf1, N2, PD2, PD2, 1.f);
    gemm(routerp0, w1_w, w1_b, router1, 1, PD2, PD2, 1.f);

    // ---- propagation 1 + layer 2
    hipLaunchKernelGGL(make_tgp1, dim3((N2 * PD2 + 255) / 256), dim3(256), 0, stream,
                       tf1, rou1, router1, tgp1);
    gemm(tgp1, w2_w, w2_b, tf2, N2, PD2, PD2, 1.f);

    // ---- final features (written straight into d_out)
    hipLaunchKernelGGL(build_final, dim3((N2 * FD + 255) / 256), dim3(256), 0, stream,
                       tg_X, tf1, tf2, outF);

    // ---- attention 2
    gemm(outF, pq_w, pq_b, q2b, N2, DZ, FD, INV_TEMP);
    gemm(lm_X, pk_w, pk_b, k2b, N1, DZ, PD, 1.f);
    hipLaunchKernelGGL(make_v2, dim3((N1 + 255) / 256), dim3(256), 0, stream, lm_Y, pv_w, pv_b, v2b);
    gemm(q2b, k2b, nullptr, scores, N2, N1, DZ, 1.f);      // overwrites attr (no longer needed)
    hipLaunchKernelGGL(softmax_pv, dim3(N2), dim3(256), 0, stream, scores, v2b, out, N1);
}

// Round 3
// 388.986 us; speedup vs baseline: 2.7246x; 2.7246x over previous
//
#include <hip/hip_runtime.h>

#define N1 4096
#define N2 2048
#define PD 256
#define DZ 128
#define PD2 258
#define PD2P 264     // 258 padded to mult of 8 (16B-aligned bf16 rows)
#define FD 772
#define FDP 776

typedef short s8v __attribute__((ext_vector_type(8)));   // 8 bf16 (4 VGPRs)
typedef float f32x4 __attribute__((ext_vector_type(4)));

// f32 -> bf16 (RNE) as raw short
__device__ __forceinline__ short f2b(float f) {
    union { float f; unsigned u; } v; v.f = f;
    unsigned r = v.u + 0x7fffu + ((v.u >> 16) & 1u);
    return (short)(r >> 16);
}

// ---------------------------------------------------------------- MFMA GEMM
// out[M,N] = scale * (A[M,KP](bf16) @ B[N,KP](bf16)^T + bias[N])
// KP = padded K (mult of 8, zero-filled pads). outF (f32) and/or outB (bf16),
// both with row stride ldo.
template<int BM, int BN>
__global__ __launch_bounds__(256) void gemm_mfma(
    const short* __restrict__ A, const short* __restrict__ B,
    const float* __restrict__ bias,
    float* __restrict__ outF, short* __restrict__ outB,
    int M, int N, int KP, int ldo, float scale)
{
    constexpr int LDS_LD = 40;            // 32 + 8 pad (80B rows, 16B aligned)
    __shared__ short Als[BM][LDS_LD];
    __shared__ short Bls[BN][LDS_LD];
    constexpr int WM = BM / 2, WN = BN / 2;
    constexpr int MT = WM / 16, NT = WN / 16;
    const int tid = threadIdx.x;
    const int wave = tid >> 6, lane = tid & 63;
    const int wm = wave >> 1, wn = wave & 1;
    const int lm = lane & 15, lq = lane >> 4;
    const int row0 = blockIdx.y * BM, col0 = blockIdx.x * BN;

    f32x4 acc[MT][NT];
    const f32x4 zero4 = {0.f, 0.f, 0.f, 0.f};
#pragma unroll
    for (int mt = 0; mt < MT; ++mt)
#pragma unroll
        for (int nt = 0; nt < NT; ++nt) acc[mt][nt] = zero4;

    const s8v zero8 = {0, 0, 0, 0, 0, 0, 0, 0};
    for (int k0 = 0; k0 < KP; k0 += 32) {
        // stage A tile [BM x 32]
#pragma unroll
        for (int i = 0; i < BM / 64; ++i) {
            int idx = i * 256 + tid;
            int r = idx >> 2, cg = idx & 3;
            int gr = row0 + r, gk = k0 + cg * 8;
            s8v v = zero8;
            if (gr < M && gk < KP) v = *(const s8v*)(A + (size_t)gr * KP + gk);
            *(s8v*)(&Als[r][cg * 8]) = v;
        }
        // stage B tile [BN x 32]
#pragma unroll
        for (int i = 0; i < BN / 64; ++i) {
            int idx = i * 256 + tid;
            int r = idx >> 2, cg = idx & 3;
            int gr = col0 + r, gk = k0 + cg * 8;
            s8v v = zero8;
            if (gr < N && gk < KP) v = *(const s8v*)(B + (size_t)gr * KP + gk);
            *(s8v*)(&Bls[r][cg * 8]) = v;
        }
        __syncthreads();
        s8v af[MT], bf[NT];
#pragma unroll
        for (int mt = 0; mt < MT; ++mt)
            af[mt] = *(const s8v*)(&Als[wm * WM + mt * 16 + lm][lq * 8]);
#pragma unroll
        for (int nt = 0; nt < NT; ++nt)
            bf[nt] = *(const s8v*)(&Bls[wn * WN + nt * 16 + lm][lq * 8]);
#pragma unroll
        for (int mt = 0; mt < MT; ++mt)
#pragma unroll
            for (int nt = 0; nt < NT; ++nt)
                acc[mt][nt] = __builtin_amdgcn_mfma_f32_16x16x32_bf16(
                    af[mt], bf[nt], acc[mt][nt], 0, 0, 0);
        __syncthreads();
    }
    // epilogue: C/D layout col=lane&15, row=(lane>>4)*4+reg
#pragma unroll
    for (int mt = 0; mt < MT; ++mt) {
#pragma unroll
        for (int nt = 0; nt < NT; ++nt) {
            int c = col0 + wn * WN + nt * 16 + lm;
            if (c >= N) continue;
            float bv = bias ? bias[c] : 0.f;
#pragma unroll
            for (int i = 0; i < 4; ++i) {
                int r = row0 + wm * WM + mt * 16 + lq * 4 + i;
                if (r >= M) continue;
                float v = scale * (acc[mt][nt][i] + bv);
                if (outF) outF[(size_t)r * ldo + c] = v;
                if (outB) outB[(size_t)r * ldo + c] = f2b(v);
            }
        }
    }
}

// ---------------------------------------------------------------- prep
// lmFT[c][r] = lm_feature[r][c] (f32 + bf16)
__global__ void prep_lmFT(const float* __restrict__ lmX, const float* __restrict__ lmY,
                          float* __restrict__ lmFT, short* __restrict__ lmFTb) {
    int idx = blockIdx.x * blockDim.x + threadIdx.x;
    if (idx >= PD2 * N1) return;
    int c = idx >> 12;
    int r = idx & (N1 - 1);
    float v = (c < PD) ? lmX[r * PD + c] : lmY[r * 2 + (c - PD)];
    lmFT[idx] = v;
    lmFTb[idx] = f2b(v);
}

// generic f32 -> bf16 with K padding (rows*KP elements, pad cols zeroed)
__global__ void cvt_pad(const float* __restrict__ in, short* __restrict__ out,
                        int K, int KP, int total) {
    int idx = blockIdx.x * blockDim.x + threadIdx.x;
    if (idx >= total) return;
    int r = idx / KP, c = idx - r * KP;
    out[idx] = (c < K) ? f2b(in[(size_t)r * K + c]) : (short)0;
}

__global__ void prep_delay(const float* __restrict__ lm_delay, const float* __restrict__ tg_delay,
                           const float* __restrict__ g1, const float* __restrict__ g2,
                           const float* __restrict__ g3, const float* __restrict__ al,
                           const float* __restrict__ be,
                           float* __restrict__ dscore, float* __restrict__ rou0,
                           float* __restrict__ rou1) {
    float a = al[0], b = be[0];
    int i = blockIdx.x * blockDim.x + threadIdx.x;
    if (i < N1) dscore[i] = __expf(-g1[0] * (a * lm_delay[i] + b));
    if (i < N2) {
        float t = a * tg_delay[i] + b;
        rou0[i] = __expf(-g2[0] * t);
        rou1[i] = __expf(-g3[0] * t);
    }
}

__global__ __launch_bounds__(256) void sum_reduce(const float* __restrict__ in,
                                                  float* __restrict__ out, int n) {
    __shared__ float red[256];
    int tid = threadIdx.x;
    float s = 0.f;
    for (int i = tid; i < n; i += 256) s += in[i];
    red[tid] = s; __syncthreads();
    for (int o = 128; o > 0; o >>= 1) { if (tid < o) red[tid] += red[tid + o]; __syncthreads(); }
    if (tid == 0) out[0] = red[0];
}

__global__ __launch_bounds__(256) void router_kernel(const float* __restrict__ lmFT,
                                                     const float* __restrict__ dscore,
                                                     const float* __restrict__ scal,
                                                     float* __restrict__ router0,
                                                     float* __restrict__ routerp0) {
    int c = blockIdx.x;
    const float* rowp = lmFT + (size_t)c * N1;
    __shared__ float r1[256], r2[256];
    int tid = threadIdx.x;
    float s1 = 0.f, s2 = 0.f;
    for (int i = tid; i < N1; i += 256) {
        float v = rowp[i];
        s1 += v;
        s2 += dscore[i] * v;
    }
    r1[tid] = s1; r2[tid] = s2; __syncthreads();
    for (int o = 128; o > 0; o >>= 1) {
        if (tid < o) { r1[tid] += r1[tid + o]; r2[tid] += r2[tid + o]; }
        __syncthreads();
    }
    if (tid == 0) {
        float r0 = r1[0] / (float)N1;
        router0[c] = r0;
        routerp0[c] = (r2[0] + r0) / (1.f + scal[0] + 1e-12f);
    }
}

// router1[c] = routerp0 . w1_w[c,:] + w1_b[c]   (258x258, tiny)
__global__ __launch_bounds__(256) void router1_kernel(const float* __restrict__ rp0,
                                                      const float* __restrict__ w1w,
                                                      const float* __restrict__ w1b,
                                                      float* __restrict__ router1) {
    for (int c = threadIdx.x; c < PD2; c += 256) {
        float s = w1b[c];
        const float* wr = w1w + (size_t)c * PD2;
        for (int k = 0; k < PD2; ++k) s += rp0[k] * wr[k];
        router1[c] = s;
    }
}

// ---------------------------------------------------------------- softmax
// attr = exp(softmax(scores)) -> bf16, attr_sum (f32, pre-rounding)
__global__ __launch_bounds__(256) void softmax_attr(const float* __restrict__ scores,
                                                    short* __restrict__ attr_b,
                                                    float* __restrict__ attr_sum) {
    int row = blockIdx.x;
    const float* s = scores + (size_t)row * N1;
    short* ab = attr_b + (size_t)row * N1;
    __shared__ float red[256];
    int tid = threadIdx.x;
    float m = -1e30f;
    for (int i = tid; i < N1; i += 256) m = fmaxf(m, s[i]);
    red[tid] = m; __syncthreads();
    for (int o = 128; o > 0; o >>= 1) { if (tid < o) red[tid] = fmaxf(red[tid], red[tid + o]); __syncthreads(); }
    m = red[0]; __syncthreads();
    float z = 0.f;
    for (int i = tid; i < N1; i += 256) z += __expf(s[i] - m);
    red[tid] = z; __syncthreads();
    for (int o = 128; o > 0; o >>= 1) { if (tid < o) red[tid] += red[tid + o]; __syncthreads(); }
    float invZ = 1.f / red[0]; __syncthreads();
    float asum = 0.f;
    for (int i = tid; i < N1; i += 256) {
        float a = __expf(__expf(s[i] - m) * invZ);
        ab[i] = f2b(a);
        asum += a;
    }
    red[tid] = asum; __syncthreads();
    for (int o = 128; o > 0; o >>= 1) { if (tid < o) red[tid] += red[tid + o]; __syncthreads(); }
    if (tid == 0) attr_sum[row] = red[0];
}

// y_pred[row] = softmax(scores[row]) @ v2
__global__ __launch_bounds__(256) void softmax_pv(const float* __restrict__ scores,
                                                  const float* __restrict__ v2,
                                                  float* __restrict__ yout) {
    int row = blockIdx.x;
    const float* s = scores + (size_t)row * N1;
    __shared__ float red[256];
    int tid = threadIdx.x;
    float m = -1e30f;
    for (int i = tid; i < N1; i += 256) m = fmaxf(m, s[i]);
    red[tid] = m; __syncthreads();
    for (int o = 128; o > 0; o >>= 1) { if (tid < o) red[tid] = fmaxf(red[tid], red[tid + o]); __syncthreads(); }
    m = red[0]; __syncthreads();
    float z = 0.f, y0 = 0.f, y1 = 0.f;
    for (int i = tid; i < N1; i += 256) {
        float e = __expf(s[i] - m);
        z += e;
        y0 += e * v2[2 * i];
        y1 += e * v2[2 * i + 1];
    }
    red[tid] = z; __syncthreads();
    for (int o = 128; o > 0; o >>= 1) { if (tid < o) red[tid] += red[tid + o]; __syncthreads(); }
    z = red[0]; __syncthreads();
    red[tid] = y0; __syncthreads();
    for (int o = 128; o > 0; o >>= 1) { if (tid < o) red[tid] += red[tid + o]; __syncthreads(); }
    y0 = red[0]; __syncthreads();
    red[tid] = y1; __syncthreads();
    for (int o = 128; o > 0; o >>= 1) { if (tid < o) red[tid] += red[tid + o]; __syncthreads(); }
    y1 = red[0];
    if (tid == 0) {
        float invz = 1.f / z;
        yout[2 * row] = y0 * invz;
        yout[2 * row + 1] = y1 * invz;
    }
}

// ---------------------------------------------------------------- elementwise
// tgp0_b = bf16( (AP + tgF0 + rou0*router0) / (1+attr_sum+rou0+eps) ), padded to PD2P
__global__ void fix_tgp0(const float* __restrict__ ap, const float* __restrict__ tgX,
                         const float* __restrict__ rou0, const float* __restrict__ router0,
                         const float* __restrict__ attr_sum, short* __restrict__ outb) {
    int idx = blockIdx.x * blockDim.x + threadIdx.x;
    if (idx >= N2 * PD2P) return;
    int r = idx / PD2P, c = idx - r * PD2P;
    if (c >= PD2) { outb[idx] = 0; return; }
    float t0 = (c < PD) ? tgX[r * PD + c] : 0.f;
    float deg = 1.f + attr_sum[r] + rou0[r];
    float v = (ap[(size_t)r * PD2 + c] + t0 + rou0[r] * router0[c]) / (deg + 1e-12f);
    outb[idx] = f2b(v);
}

// tgp1_b = bf16( (tf1 + rou1*router1) / (1+rou1+eps) ), padded
__global__ void make_tgp1(const float* __restrict__ tf1, const float* __restrict__ rou1,
                          const float* __restrict__ router1, short* __restrict__ outb) {
    int idx = blockIdx.x * blockDim.x + threadIdx.x;
    if (idx >= N2 * PD2P) return;
    int r = idx / PD2P, c = idx - r * PD2P;
    if (c >= PD2) { outb[idx] = 0; return; }
    float v = (tf1[(size_t)r * PD2 + c] + rou1[r] * router1[c]) / (1.f + rou1[r] + 1e-12f);
    outb[idx] = f2b(v);
}

// final = [tgX | tf1 | tf2] -> d_out (f32) + padded bf16 copy
__global__ void build_final(const float* __restrict__ tgX, const float* __restrict__ tf1,
                            const float* __restrict__ tf2, float* __restrict__ outF,
                            short* __restrict__ outb) {
    int idx = blockIdx.x * blockDim.x + threadIdx.x;
    if (idx >= N2 * FDP) return;
    int r = idx / FDP, c = idx - r * FDP;
    if (c >= FD) { outb[idx] = 0; return; }
    float v;
    if (c < PD) v = tgX[r * PD + c];
    else if (c < PD + PD2) v = tf1[(size_t)r * PD2 + (c - PD)];
    else v = tf2[(size_t)r * PD2 + (c - PD - PD2)];
    outF[(size_t)r * FD + c] = v;
    outb[idx] = f2b(v);
}

__global__ void make_v2(const float* __restrict__ lmY, const float* __restrict__ pvw,
                        const float* __restrict__ pvb, float* __restrict__ v2) {
    int i = blockIdx.x * blockDim.x + threadIdx.x;
    if (i >= N1) return;
    float y0 = lmY[2 * i], y1 = lmY[2 * i + 1];
    v2[2 * i]     = pvw[0] * y0 + pvw[1] * y1 + pvb[0];
    v2[2 * i + 1] = pvw[2] * y0 + pvw[3] * y1 + pvb[1];
}

// ---------------------------------------------------------------- launch
extern "C" void kernel_launch(void* const* d_in, const int* in_sizes, int n_in,
                              void* d_out, int out_size, void* d_ws, size_t ws_size,
                              hipStream_t stream) {
    const float* lm_X = (const float*)d_in[0];
    const float* lm_Y = (const float*)d_in[1];
    const float* tg_X = (const float*)d_in[2];
    const float* lm_delay = (const float*)d_in[4];
    const float* tg_delay = (const float*)d_in[5];
    const float* aq_w = (const float*)d_in[6];
    const float* aq_b = (const float*)d_in[7];
    const float* ak_w = (const float*)d_in[8];
    const float* ak_b = (const float*)d_in[9];
    const float* w1_w = (const float*)d_in[10];
    const float* w1_b = (const float*)d_in[11];
    const float* w2_w = (const float*)d_in[12];
    const float* w2_b = (const float*)d_in[13];
    const float* pq_w = (const float*)d_in[14];
    const float* pq_b = (const float*)d_in[15];
    const float* pk_w = (const float*)d_in[16];
    const float* pk_b = (const float*)d_in[17];
    const float* pv_w = (const float*)d_in[18];
    const float* pv_b = (const float*)d_in[19];
    const float* g1 = (const float*)d_in[20];
    const float* g2 = (const float*)d_in[21];
    const float* g3 = (const float*)d_in[22];
    const float* al = (const float*)d_in[23];
    const float* be = (const float*)d_in[24];

    float* out = (float*)d_out;
    float* outF = out + (size_t)N2 * 2;

    char* base = (char*)d_ws;
    size_t off = 0;
    auto allocF = [&](size_t n) -> float* {
        float* p = (float*)(base + off);
        off += (n * 4 + 255) / 256 * 256;
        return p;
    };
    auto allocS = [&](size_t n) -> short* {
        short* p = (short*)(base + off);
        off += (n * 2 + 255) / 256 * 256;
        return p;
    };

    float* scores   = allocF((size_t)N2 * N1);    // reused for both attentions
    float* lmFT     = allocF((size_t)PD2 * N1);
    short* lmFTb    = allocS((size_t)PD2 * N1);
    short* attr_b   = allocS((size_t)N2 * N1);
    short* lmXb     = allocS((size_t)N1 * PD);
    short* tgXb     = allocS((size_t)N2 * PD);
    short* qb_b     = allocS((size_t)N2 * DZ);
    short* kb_b     = allocS((size_t)N1 * DZ);
    short* q2_b     = allocS((size_t)N2 * DZ);
    short* k2_b     = allocS((size_t)N1 * DZ);
    float* tgp0f    = allocF((size_t)N2 * PD2);
    short* tgp0b    = allocS((size_t)N2 * PD2P);
    float* tf1      = allocF((size_t)N2 * PD2);
    short* tgp1b    = allocS((size_t)N2 * PD2P);
    float* tf2      = allocF((size_t)N2 * PD2);
    short* finalFb  = allocS((size_t)N2 * FDP);
    short* aqwb     = allocS((size_t)DZ * PD);
    short* akwb     = allocS((size_t)DZ * PD);
    short* pkwb     = allocS((size_t)DZ * PD);
    short* pqwb     = allocS((size_t)DZ * FDP);
    short* w1wb     = allocS((size_t)PD2 * PD2P);
    short* w2wb     = allocS((size_t)PD2 * PD2P);
    float* v2b      = allocF((size_t)N1 * 2);
    float* router0  = allocF(PD2);
    float* routerp0 = allocF(PD2);
    float* router1  = allocF(PD2);
    float* dscore   = allocF(N1);
    float* rou0     = allocF(N2);
    float* rou1     = allocF(N2);
    float* attr_sum = allocF(N2);
    float* scal     = allocF(8);

    const float INV_TEMP = 0.08838834764831845f; // 1/sqrt(128)

    auto cvt = [&](const float* in, short* o, int K, int KP, int rows) {
        int total = rows * KP;
        hipLaunchKernelGGL(cvt_pad, dim3((total + 255) / 256), dim3(256), 0, stream,
                           in, o, K, KP, total);
    };
    auto g128 = [&](const short* A, const short* B, const float* bias,
                    float* oF, short* oB, int M, int N, int KP, int ldo, float scale) {
        dim3 g((N + 127) / 128, (M + 127) / 128);
        hipLaunchKernelGGL((gemm_mfma<128, 128>), g, dim3(256), 0, stream,
                           A, B, bias, oF, oB, M, N, KP, ldo, scale);
    };
    auto g64 = [&](const short* A, const short* B, const float* bias,
                   float* oF, short* oB, int M, int N, int KP, int ldo, float scale) {
        dim3 g((N + 63) / 64, (M + 63) / 64);
        hipLaunchKernelGGL((gemm_mfma<64, 64>), g, dim3(256), 0, stream,
                           A, B, bias, oF, oB, M, N, KP, ldo, scale);
    };

    // ---- prep + conversions
    hipLaunchKernelGGL(prep_lmFT, dim3((PD2 * N1 + 255) / 256), dim3(256), 0, stream,
                       lm_X, lm_Y, lmFT, lmFTb);
    hipLaunchKernelGGL(prep_delay, dim3((N1 + 255) / 256), dim3(256), 0, stream,
                       lm_delay, tg_delay, g1, g2, g3, al, be, dscore, rou0, rou1);
    hipLaunchKernelGGL(sum_reduce, dim3(1), dim3(256), 0, stream, dscore, scal, N1);
    hipLaunchKernelGGL(router_kernel, dim3(PD2), dim3(256), 0, stream,
                       lmFT, dscore, scal, router0, routerp0);
    cvt(lm_X, lmXb, PD, PD, N1);
    cvt(tg_X, tgXb, PD, PD, N2);
    cvt(aq_w, aqwb, PD, PD, DZ);
    cvt(ak_w, akwb, PD, PD, DZ);
    cvt(pk_w, pkwb, PD, PD, DZ);
    cvt(pq_w, pqwb, FD, FDP, DZ);
    cvt(w1_w, w1wb, PD2, PD2P, PD2);
    cvt(w2_w, w2wb, PD2, PD2P, PD2);

    // ---- attention 1
    g64(lmXb, akwb, ak_b, nullptr, kb_b, N1, DZ, PD, DZ, 1.f);
    g64(tgXb, aqwb, aq_b, nullptr, qb_b, N2, DZ, PD, DZ, INV_TEMP);
    g128(qb_b, kb_b, nullptr, scores, nullptr, N2, N1, DZ, N1, 1.f);
    hipLaunchKernelGGL(softmax_attr, dim3(N2), dim3(256), 0, stream, scores, attr_b, attr_sum);

    // ---- propagation 0:  AP = attr @ lm_feature
    g64(attr_b, lmFTb, nullptr, tgp0f, nullptr, N2, PD2, N1, PD2, 1.f);
    hipLaunchKernelGGL(fix_tgp0, dim3((N2 * PD2P + 255) / 256), dim3(256), 0, stream,
                       tgp0f, tg_X, rou0, router0, attr_sum, tgp0b);

    // ---- layer 1
    g64(tgp0b, w1wb, w1_b, tf1, nullptr, N2, PD2, PD2P, PD2, 1.f);
    hipLaunchKernelGGL(router1_kernel, dim3(1), dim3(256), 0, stream,
                       routerp0, w1_w, w1_b, router1);

    // ---- propagation 1 + layer 2
    hipLaunchKernelGGL(make_tgp1, dim3((N2 * PD2P + 255) / 256), dim3(256), 0, stream,
                       tf1, rou1, router1, tgp1b);
    g64(tgp1b, w2wb, w2_b, tf2, nullptr, N2, PD2, PD2P, PD2, 1.f);

    // ---- final features
    hipLaunchKernelGGL(build_final, dim3((N2 * FDP + 255) / 256), dim3(256), 0, stream,
                       tg_X, tf1, tf2, outF, finalFb);

    // ---- attention 2
    g64(finalFb, pqwb, pq_b, nullptr, q2_b, N2, DZ, FDP, DZ, INV_TEMP);
    g64(lmXb, pkwb, pk_b, nullptr, k2_b, N1, DZ, PD, DZ, 1.f);
    hipLaunchKernelGGL(make_v2, dim3((N1 + 255) / 256), dim3(256), 0, stream,
                       lm_Y, pv_w, pv_b, v2b);
    g128(q2_b, k2_b, nullptr, scores, nullptr, N2, N1, DZ, N1, 1.f);
    hipLaunchKernelGGL(softmax_pv, dim3(N2), dim3(256), 0, stream, scores, v2b, out);
}

// Round 4
// 329.933 us; speedup vs baseline: 3.2122x; 1.1790x over previous
//
#include <hip/hip_runtime.h>

#define N1 4096
#define N2 2048
#define PD 256
#define DZ 128
#define PD2 258
#define PD2P 264     // 258 padded to mult of 8
#define FD 772
#define FDP 776
#define APN 272      // lmFT rows padded to 17*16 for AP kernel
#define APLD 72      // LDS row stride (shorts) for AP kernel (2-way-conflict free)
#define SPLITS 8

typedef short s8v __attribute__((ext_vector_type(8)));   // 8 bf16 (4 VGPRs)
typedef float f32x4 __attribute__((ext_vector_type(4)));

// f32 -> bf16 (RNE) as raw short
__device__ __forceinline__ short f2b(float f) {
    union { float f; unsigned u; } v; v.f = f;
    unsigned r = v.u + 0x7fffu + ((v.u >> 16) & 1u);
    return (short)(r >> 16);
}

// ---------------------------------------------------------------- fused prep/convert
constexpr int C0 = N1 * PD;            // lmXb
constexpr int C1 = C0 + N2 * PD;       // tgXb
constexpr int C2 = C1 + DZ * PD;       // aqwb
constexpr int C3 = C2 + DZ * PD;       // akwb
constexpr int C4 = C3 + DZ * PD;       // pkwb
constexpr int C5 = C4 + DZ * FDP;      // pqwb (pad 772->776)
constexpr int C6 = C5 + PD2 * PD2P;    // w1wb (pad 258->264)
constexpr int C7 = C6 + PD2 * PD2P;    // w2wb
constexpr int C8 = C7 + APN * N1;      // lmFT f32 [258][4096] + lmFTb [272][4096]
constexpr int C9 = C8 + N1;            // delay scores + v2

__global__ __launch_bounds__(256) void cvt_all(
    const float* __restrict__ lmX, const float* __restrict__ lmY,
    const float* __restrict__ tgX,
    const float* __restrict__ aqw, const float* __restrict__ akw,
    const float* __restrict__ pkw, const float* __restrict__ pqw,
    const float* __restrict__ w1w, const float* __restrict__ w2w,
    const float* __restrict__ lmd, const float* __restrict__ tgd,
    const float* __restrict__ g1, const float* __restrict__ g2,
    const float* __restrict__ g3, const float* __restrict__ al,
    const float* __restrict__ be,
    const float* __restrict__ pvw, const float* __restrict__ pvb,
    short* __restrict__ lmXb, short* __restrict__ tgXb,
    short* __restrict__ aqwb, short* __restrict__ akwb,
    short* __restrict__ pkwb, short* __restrict__ pqwb,
    short* __restrict__ w1wb, short* __restrict__ w2wb,
    float* __restrict__ lmFT, short* __restrict__ lmFTb,
    float* __restrict__ dscore, float* __restrict__ rou0,
    float* __restrict__ rou1, float* __restrict__ v2b)
{
    int i = blockIdx.x * 256 + threadIdx.x;
    if (i < C0) { lmXb[i] = f2b(lmX[i]); return; }
    if (i < C1) { int j = i - C0; tgXb[j] = f2b(tgX[j]); return; }
    if (i < C2) { int j = i - C1; aqwb[j] = f2b(aqw[j]); return; }
    if (i < C3) { int j = i - C2; akwb[j] = f2b(akw[j]); return; }
    if (i < C4) { int j = i - C3; pkwb[j] = f2b(pkw[j]); return; }
    if (i < C5) { int j = i - C4; int r = j / FDP, c = j - r * FDP;
                  pqwb[j] = (c < FD) ? f2b(pqw[r * FD + c]) : (short)0; return; }
    if (i < C6) { int j = i - C5; int r = j / PD2P, c = j - r * PD2P;
                  w1wb[j] = (c < PD2) ? f2b(w1w[r * PD2 + c]) : (short)0; return; }
    if (i < C7) { int j = i - C6; int r = j / PD2P, c = j - r * PD2P;
                  w2wb[j] = (c < PD2) ? f2b(w2w[r * PD2 + c]) : (short)0; return; }
    if (i < C8) { int j = i - C7; int c = j >> 12, r = j & (N1 - 1);
                  float v = 0.f;
                  if (c < PD) v = lmX[r * PD + c];
                  else if (c < PD2) v = lmY[r * 2 + (c - PD)];
                  if (c < PD2) lmFT[j] = v;
                  lmFTb[j] = f2b(v); return; }
    if (i < C9) { int j = i - C8;   // j in [0,4096)
                  float a = al[0], b = be[0];
                  dscore[j] = __expf(-g1[0] * (a * lmd[j] + b));
                  float y0 = lmY[2 * j], y1 = lmY[2 * j + 1];
                  v2b[2 * j]     = pvw[0] * y0 + pvw[1] * y1 + pvb[0];
                  v2b[2 * j + 1] = pvw[2] * y0 + pvw[3] * y1 + pvb[1];
                  if (j < N2) { float t = a * tgd[j] + b;
                                rou0[j] = __expf(-g2[0] * t);
                                rou1[j] = __expf(-g3[0] * t); }
                  return; }
}

__global__ __launch_bounds__(256) void sum_reduce(const float* __restrict__ in,
                                                  float* __restrict__ out, int n) {
    __shared__ float red[256];
    int tid = threadIdx.x;
    float s = 0.f;
    for (int i = tid; i < n; i += 256) s += in[i];
    red[tid] = s; __syncthreads();
    for (int o = 128; o > 0; o >>= 1) { if (tid < o) red[tid] += red[tid + o]; __syncthreads(); }
    if (tid == 0) out[0] = red[0];
}

__global__ __launch_bounds__(256) void router_kernel(const float* __restrict__ lmFT,
                                                     const float* __restrict__ dscore,
                                                     const float* __restrict__ scal,
                                                     float* __restrict__ router0,
                                                     float* __restrict__ routerp0) {
    int c = blockIdx.x;
    const float* rowp = lmFT + (size_t)c * N1;
    __shared__ float r1[256], r2[256];
    int tid = threadIdx.x;
    float s1 = 0.f, s2 = 0.f;
    for (int i = tid; i < N1; i += 256) {
        float v = rowp[i];
        s1 += v;
        s2 += dscore[i] * v;
    }
    r1[tid] = s1; r2[tid] = s2; __syncthreads();
    for (int o = 128; o > 0; o >>= 1) {
        if (tid < o) { r1[tid] += r1[tid + o]; r2[tid] += r2[tid + o]; }
        __syncthreads();
    }
    if (tid == 0) {
        float r0 = r1[0] / (float)N1;
        router0[c] = r0;
        routerp0[c] = (r2[0] + r0) / (1.f + scal[0] + 1e-12f);
    }
}

__global__ __launch_bounds__(256) void router1_kernel(const float* __restrict__ rp0,
                                                      const float* __restrict__ w1w,
                                                      const float* __restrict__ w1b,
                                                      float* __restrict__ router1) {
    for (int c = threadIdx.x; c < PD2; c += 256) {
        float s = w1b[c];
        const float* wr = w1w + (size_t)c * PD2;
        for (int k = 0; k < PD2; ++k) s += rp0[k] * wr[k];
        router1[c] = s;
    }
}

// ---------------------------------------------------------------- generic MFMA GEMM
// out[M,N] = scale * (A[M,KP](bf16) @ B[N,KP](bf16)^T + bias[N])
template<int BM, int BN>
__global__ __launch_bounds__(256) void gemm_mfma(
    const short* __restrict__ A, const short* __restrict__ B,
    const float* __restrict__ bias,
    float* __restrict__ outF, short* __restrict__ outB,
    int M, int N, int KP, int ldo, float scale)
{
    constexpr int LDS_LD = 40;
    __shared__ short Als[BM][LDS_LD];
    __shared__ short Bls[BN][LDS_LD];
    constexpr int WM = BM / 2, WN = BN / 2;
    constexpr int MT = WM / 16, NT = WN / 16;
    const int tid = threadIdx.x;
    const int wave = tid >> 6, lane = tid & 63;
    const int wm = wave >> 1, wn = wave & 1;
    const int lm = lane & 15, lq = lane >> 4;
    const int row0 = blockIdx.y * BM, col0 = blockIdx.x * BN;

    f32x4 acc[MT][NT];
    const f32x4 zero4 = {0.f, 0.f, 0.f, 0.f};
#pragma unroll
    for (int mt = 0; mt < MT; ++mt)
#pragma unroll
        for (int nt = 0; nt < NT; ++nt) acc[mt][nt] = zero4;

    const s8v zero8 = {0, 0, 0, 0, 0, 0, 0, 0};
    for (int k0 = 0; k0 < KP; k0 += 32) {
#pragma unroll
        for (int i = 0; i < BM / 64; ++i) {
            int idx = i * 256 + tid;
            int r = idx >> 2, cg = idx & 3;
            int gr = row0 + r, gk = k0 + cg * 8;
            s8v v = zero8;
            if (gr < M && gk < KP) v = *(const s8v*)(A + (size_t)gr * KP + gk);
            *(s8v*)(&Als[r][cg * 8]) = v;
        }
#pragma unroll
        for (int i = 0; i < BN / 64; ++i) {
            int idx = i * 256 + tid;
            int r = idx >> 2, cg = idx & 3;
            int gr = col0 + r, gk = k0 + cg * 8;
            s8v v = zero8;
            if (gr < N && gk < KP) v = *(const s8v*)(B + (size_t)gr * KP + gk);
            *(s8v*)(&Bls[r][cg * 8]) = v;
        }
        __syncthreads();
        s8v af[MT], bf[NT];
#pragma unroll
        for (int mt = 0; mt < MT; ++mt)
            af[mt] = *(const s8v*)(&Als[wm * WM + mt * 16 + lm][lq * 8]);
#pragma unroll
        for (int nt = 0; nt < NT; ++nt)
            bf[nt] = *(const s8v*)(&Bls[wn * WN + nt * 16 + lm][lq * 8]);
#pragma unroll
        for (int mt = 0; mt < MT; ++mt)
#pragma unroll
            for (int nt = 0; nt < NT; ++nt)
                acc[mt][nt] = __builtin_amdgcn_mfma_f32_16x16x32_bf16(
                    af[mt], bf[nt], acc[mt][nt], 0, 0, 0);
        __syncthreads();
    }
#pragma unroll
    for (int mt = 0; mt < MT; ++mt) {
#pragma unroll
        for (int nt = 0; nt < NT; ++nt) {
            int c = col0 + wn * WN + nt * 16 + lm;
            if (c >= N) continue;
            float bv = bias ? bias[c] : 0.f;
#pragma unroll
            for (int i = 0; i < 4; ++i) {
                int r = row0 + wm * WM + mt * 16 + lq * 4 + i;
                if (r >= M) continue;
                float v = scale * (acc[mt][nt][i] + bv);
                if (outF) outF[(size_t)r * ldo + c] = v;
                if (outB) outB[(size_t)r * ldo + c] = f2b(v);
            }
        }
    }
}

// ---------------------------------------------------------------- AP split-K GEMM
// part[s][r][c] = sum_{k in chunk s} attr[r][k] * lmFT[c][k]
// block: 128 rows x 272 cols, 4 waves (wave w: rows w*32..w*32+32), BK=64
__global__ __launch_bounds__(256) void ap_gemm(const short* __restrict__ attr,
                                               const short* __restrict__ lmFTb,
                                               float* __restrict__ part)
{
    __shared__ short Als[128 * APLD];   // 18.4 KB
    __shared__ short Bls[APN * APLD];   // 39.2 KB
    const int tid = threadIdx.x;
    const int wave = tid >> 6, lane = tid & 63;
    const int lm = lane & 15, lq = lane >> 4;
    const int s = blockIdx.x;           // split 0..7
    const int row0 = blockIdx.y * 128;
    const int kbase = s * (N1 / SPLITS);
    f32x4 acc0[17], acc1[17];
    const f32x4 zero4 = {0.f, 0.f, 0.f, 0.f};
#pragma unroll
    for (int nt = 0; nt < 17; ++nt) { acc0[nt] = zero4; acc1[nt] = zero4; }

    for (int it = 0; it < (N1 / SPLITS) / 64; ++it) {
        int k0 = kbase + it * 64;
#pragma unroll
        for (int l = 0; l < 4; ++l) {          // A: 128 rows x 8 s8v-groups
            int id = l * 256 + tid;
            int r = id >> 3, g = id & 7;
            *(s8v*)(&Als[r * APLD + g * 8]) =
                *(const s8v*)(attr + (size_t)(row0 + r) * N1 + k0 + g * 8);
        }
#pragma unroll
        for (int l = 0; l < 9; ++l) {          // B: 272 rows x 8 groups = 2176
            int id = l * 256 + tid;
            if (id < APN * 8) {
                int r = id >> 3, g = id & 7;
                *(s8v*)(&Bls[r * APLD + g * 8]) =
                    *(const s8v*)(lmFTb + (size_t)r * N1 + k0 + g * 8);
            }
        }
        __syncthreads();
        s8v a00 = *(const s8v*)(&Als[(wave * 32 + lm) * APLD + lq * 8]);
        s8v a01 = *(const s8v*)(&Als[(wave * 32 + lm) * APLD + 32 + lq * 8]);
        s8v a10 = *(const s8v*)(&Als[(wave * 32 + 16 + lm) * APLD + lq * 8]);
        s8v a11 = *(const s8v*)(&Als[(wave * 32 + 16 + lm) * APLD + 32 + lq * 8]);
#pragma unroll
        for (int nt = 0; nt < 17; ++nt) {
            s8v b0 = *(const s8v*)(&Bls[(nt * 16 + lm) * APLD + lq * 8]);
            s8v b1 = *(const s8v*)(&Bls[(nt * 16 + lm) * APLD + 32 + lq * 8]);
            acc0[nt] = __builtin_amdgcn_mfma_f32_16x16x32_bf16(a00, b0, acc0[nt], 0, 0, 0);
            acc0[nt] = __builtin_amdgcn_mfma_f32_16x16x32_bf16(a01, b1, acc0[nt], 0, 0, 0);
            acc1[nt] = __builtin_amdgcn_mfma_f32_16x16x32_bf16(a10, b0, acc1[nt], 0, 0, 0);
            acc1[nt] = __builtin_amdgcn_mfma_f32_16x16x32_bf16(a11, b1, acc1[nt], 0, 0, 0);
        }
        __syncthreads();
    }
    float* op = part + (size_t)s * N2 * APN;
#pragma unroll
    for (int nt = 0; nt < 17; ++nt) {
        int c = nt * 16 + lm;
#pragma unroll
        for (int i = 0; i < 4; ++i) {
            int r = row0 + wave * 32 + lq * 4 + i;
            op[(size_t)r * APN + c] = acc0[nt][i];
            op[(size_t)(r + 16) * APN + c] = acc1[nt][i];
        }
    }
}

// ---------------------------------------------------------------- softmax (attention 1)
__global__ __launch_bounds__(256) void softmax_attr(const float* __restrict__ scores,
                                                    short* __restrict__ attr_b,
                                                    float* __restrict__ attr_sum) {
    int row = blockIdx.x;
    const float* s = scores + (size_t)row * N1;
    short* ab = attr_b + (size_t)row * N1;
    __shared__ float red[256];
    int tid = threadIdx.x;
    float m = -1e30f;
    for (int i = tid; i < N1; i += 256) m = fmaxf(m, s[i]);
    red[tid] = m; __syncthreads();
    for (int o = 128; o > 0; o >>= 1) { if (tid < o) red[tid] = fmaxf(red[tid], red[tid + o]); __syncthreads(); }
    m = red[0]; __syncthreads();
    float z = 0.f;
    for (int i = tid; i < N1; i += 256) z += __expf(s[i] - m);
    red[tid] = z; __syncthreads();
    for (int o = 128; o > 0; o >>= 1) { if (tid < o) red[tid] += red[tid + o]; __syncthreads(); }
    float invZ = 1.f / red[0]; __syncthreads();
    float asum = 0.f;
    for (int i = tid; i < N1; i += 256) {
        float a = __expf(__expf(s[i] - m) * invZ);
        ab[i] = f2b(a);
        asum += a;
    }
    red[tid] = asum; __syncthreads();
    for (int o = 128; o > 0; o >>= 1) { if (tid < o) red[tid] += red[tid + o]; __syncthreads(); }
    if (tid == 0) attr_sum[row] = red[0];
}

// ---------------------------------------------------------------- fused attention 2
// part2[row][chunk][4] = {m, z, y0, y1} for chunk of 1024 landmarks
__global__ __launch_bounds__(256) void attn2_flash(
    const short* __restrict__ Q, const short* __restrict__ K,
    const float* __restrict__ V, float* __restrict__ part2)
{
    __shared__ short Qls[64 * 136];
    __shared__ short Kls[64 * 136];
    __shared__ float Vls[128];
    const int tid = threadIdx.x;
    const int wave = tid >> 6, lane = tid & 63;
    const int lm = lane & 15, lq = lane >> 4;
    const int chunk = blockIdx.x;       // 0..3
    const int row0 = blockIdx.y * 64;
#pragma unroll
    for (int l = 0; l < 4; ++l) {
        int id = l * 256 + tid;
        int r = id >> 4, g = id & 15;
        *(s8v*)(&Qls[r * 136 + g * 8]) = *(const s8v*)(Q + (size_t)(row0 + r) * DZ + g * 8);
    }
    __syncthreads();
    s8v af[4];
#pragma unroll
    for (int ks = 0; ks < 4; ++ks)
        af[ks] = *(const s8v*)(&Qls[(wave * 16 + lm) * 136 + ks * 32 + lq * 8]);
    float m[4], z[4], y0[4], y1[4];
#pragma unroll
    for (int i = 0; i < 4; ++i) { m[i] = -1e30f; z[i] = 0.f; y0[i] = 0.f; y1[i] = 0.f; }

    for (int t = 0; t < 16; ++t) {
        int col0 = chunk * 1024 + t * 64;
        __syncthreads();
#pragma unroll
        for (int l = 0; l < 4; ++l) {
            int id = l * 256 + tid;
            int r = id >> 4, g = id & 15;
            *(s8v*)(&Kls[r * 136 + g * 8]) = *(const s8v*)(K + (size_t)(col0 + r) * DZ + g * 8);
        }
        if (tid < 128) Vls[tid] = V[col0 * 2 + tid];
        __syncthreads();
        f32x4 acc[4];
        const f32x4 zero4 = {0.f, 0.f, 0.f, 0.f};
#pragma unroll
        for (int nt = 0; nt < 4; ++nt) acc[nt] = zero4;
#pragma unroll
        for (int nt = 0; nt < 4; ++nt)
#pragma unroll
            for (int ks = 0; ks < 4; ++ks) {
                s8v bf = *(const s8v*)(&Kls[(nt * 16 + lm) * 136 + ks * 32 + lq * 8]);
                acc[nt] = __builtin_amdgcn_mfma_f32_16x16x32_bf16(af[ks], bf, acc[nt], 0, 0, 0);
            }
        float v0[4], v1[4];
#pragma unroll
        for (int nt = 0; nt < 4; ++nt) {
            v0[nt] = Vls[(nt * 16 + lm) * 2];
            v1[nt] = Vls[(nt * 16 + lm) * 2 + 1];
        }
#pragma unroll
        for (int i = 0; i < 4; ++i) {
            float smax = fmaxf(fmaxf(acc[0][i], acc[1][i]), fmaxf(acc[2][i], acc[3][i]));
#pragma unroll
            for (int msk = 1; msk < 16; msk <<= 1)
                smax = fmaxf(smax, __shfl_xor(smax, msk, 64));
            float mnew = fmaxf(m[i], smax);
            float e0 = __expf(acc[0][i] - mnew), e1 = __expf(acc[1][i] - mnew);
            float e2 = __expf(acc[2][i] - mnew), e3 = __expf(acc[3][i] - mnew);
            float pz = e0 + e1 + e2 + e3;
            float py0 = e0 * v0[0] + e1 * v0[1] + e2 * v0[2] + e3 * v0[3];
            float py1 = e0 * v1[0] + e1 * v1[1] + e2 * v1[2] + e3 * v1[3];
#pragma unroll
            for (int msk = 1; msk < 16; msk <<= 1) {
                pz  += __shfl_xor(pz, msk, 64);
                py0 += __shfl_xor(py0, msk, 64);
                py1 += __shfl_xor(py1, msk, 64);
            }
            float alpha = __expf(m[i] - mnew);
            z[i] = z[i] * alpha + pz;
            y0[i] = y0[i] * alpha + py0;
            y1[i] = y1[i] * alpha + py1;
            m[i] = mnew;
        }
    }
    if (lm == 0) {
#pragma unroll
        for (int i = 0; i < 4; ++i) {
            int r = row0 + wave * 16 + lq * 4 + i;
            float* p = part2 + ((size_t)r * 4 + chunk) * 4;
            p[0] = m[i]; p[1] = z[i]; p[2] = y0[i]; p[3] = y1[i];
        }
    }
}

__global__ void attn2_combine(const float* __restrict__ part2, float* __restrict__ out) {
    int r = blockIdx.x * blockDim.x + threadIdx.x;
    if (r >= N2) return;
    const float* p = part2 + (size_t)r * 16;
    float M = -1e30f;
#pragma unroll
    for (int c = 0; c < 4; ++c) M = fmaxf(M, p[c * 4]);
    float Z = 0.f, Y0 = 0.f, Y1 = 0.f;
#pragma unroll
    for (int c = 0; c < 4; ++c) {
        float w = __expf(p[c * 4] - M);
        Z += p[c * 4 + 1] * w;
        Y0 += p[c * 4 + 2] * w;
        Y1 += p[c * 4 + 3] * w;
    }
    out[2 * r] = Y0 / Z;
    out[2 * r + 1] = Y1 / Z;
}

// ---------------------------------------------------------------- elementwise
// tgp0_b = bf16( (sum_s part + tgF0 + rou0*router0) / (1+attr_sum+rou0+eps) )
__global__ void fix_tgp0(const float* __restrict__ part, const float* __restrict__ tgX,
                         const float* __restrict__ rou0, const float* __restrict__ router0,
                         const float* __restrict__ attr_sum, short* __restrict__ outb) {
    int idx = blockIdx.x * blockDim.x + threadIdx.x;
    if (idx >= N2 * PD2P) return;
    int r = idx / PD2P, c = idx - r * PD2P;
    if (c >= PD2) { outb[idx] = 0; return; }
    float ap = 0.f;
#pragma unroll
    for (int s = 0; s < SPLITS; ++s)
        ap += part[((size_t)s * N2 + r) * APN + c];
    float t0 = (c < PD) ? tgX[r * PD + c] : 0.f;
    float deg = 1.f + attr_sum[r] + rou0[r];
    float v = (ap + t0 + rou0[r] * router0[c]) / (deg + 1e-12f);
    outb[idx] = f2b(v);
}

__global__ void make_tgp1(const float* __restrict__ tf1, const float* __restrict__ rou1,
                          const float* __restrict__ router1, short* __restrict__ outb) {
    int idx = blockIdx.x * blockDim.x + threadIdx.x;
    if (idx >= N2 * PD2P) return;
    int r = idx / PD2P, c = idx - r * PD2P;
    if (c >= PD2) { outb[idx] = 0; return; }
    float v = (tf1[(size_t)r * PD2 + c] + rou1[r] * router1[c]) / (1.f + rou1[r] + 1e-12f);
    outb[idx] = f2b(v);
}

__global__ void build_final(const float* __restrict__ tgX, const float* __restrict__ tf1,
                            const float* __restrict__ tf2, float* __restrict__ outF,
                            short* __restrict__ outb) {
    int idx = blockIdx.x * blockDim.x + threadIdx.x;
    if (idx >= N2 * FDP) return;
    int r = idx / FDP, c = idx - r * FDP;
    if (c >= FD) { outb[idx] = 0; return; }
    float v;
    if (c < PD) v = tgX[r * PD + c];
    else if (c < PD + PD2) v = tf1[(size_t)r * PD2 + (c - PD)];
    else v = tf2[(size_t)r * PD2 + (c - PD - PD2)];
    outF[(size_t)r * FD + c] = v;
    outb[idx] = f2b(v);
}

// ---------------------------------------------------------------- launch
extern "C" void kernel_launch(void* const* d_in, const int* in_sizes, int n_in,
                              void* d_out, int out_size, void* d_ws, size_t ws_size,
                              hipStream_t stream) {
    const float* lm_X = (const float*)d_in[0];
    const float* lm_Y = (const float*)d_in[1];
    const float* tg_X = (const float*)d_in[2];
    const float* lm_delay = (const float*)d_in[4];
    const float* tg_delay = (const float*)d_in[5];
    const float* aq_w = (const float*)d_in[6];
    const float* aq_b = (const float*)d_in[7];
    const float* ak_w = (const float*)d_in[8];
    const float* ak_b = (const float*)d_in[9];
    const float* w1_w = (const float*)d_in[10];
    const float* w1_b = (const float*)d_in[11];
    const float* w2_w = (const float*)d_in[12];
    const float* w2_b = (const float*)d_in[13];
    const float* pq_w = (const float*)d_in[14];
    const float* pq_b = (const float*)d_in[15];
    const float* pk_w = (const float*)d_in[16];
    const float* pk_b = (const float*)d_in[17];
    const float* pv_w = (const float*)d_in[18];
    const float* pv_b = (const float*)d_in[19];
    const float* g1 = (const float*)d_in[20];
    const float* g2 = (const float*)d_in[21];
    const float* g3 = (const float*)d_in[22];
    const float* al = (const float*)d_in[23];
    const float* be = (const float*)d_in[24];

    float* out = (float*)d_out;
    float* outF = out + (size_t)N2 * 2;

    char* base = (char*)d_ws;
    size_t off = 0;
    auto allocF = [&](size_t n) -> float* {
        float* p = (float*)(base + off);
        off += (n * 4 + 255) / 256 * 256;
        return p;
    };
    auto allocS = [&](size_t n) -> short* {
        short* p = (short*)(base + off);
        off += (n * 2 + 255) / 256 * 256;
        return p;
    };

    float* scores   = allocF((size_t)N2 * N1);   // attention-1 scores; later AP partials
    float* appart   = scores;                    // SPLITS*N2*APN floats = 17.8MB < 33.5MB
    float* lmFT     = allocF((size_t)PD2 * N1);
    short* lmFTb    = allocS((size_t)APN * N1);  // [272][4096], rows 258..271 zero
    short* attr_b   = allocS((size_t)N2 * N1);
    short* lmXb     = allocS((size_t)N1 * PD);
    short* tgXb     = allocS((size_t)N2 * PD);
    short* qb_b     = allocS((size_t)N2 * DZ);
    short* kb_b     = allocS((size_t)N1 * DZ);
    short* q2_b     = allocS((size_t)N2 * DZ);
    short* k2_b     = allocS((size_t)N1 * DZ);
    short* tgp0b    = allocS((size_t)N2 * PD2P);
    float* tf1      = allocF((size_t)N2 * PD2);
    short* tgp1b    = allocS((size_t)N2 * PD2P);
    float* tf2      = allocF((size_t)N2 * PD2);
    short* finalFb  = allocS((size_t)N2 * FDP);
    short* aqwb     = allocS((size_t)DZ * PD);
    short* akwb     = allocS((size_t)DZ * PD);
    short* pkwb     = allocS((size_t)DZ * PD);
    short* pqwb     = allocS((size_t)DZ * FDP);
    short* w1wb     = allocS((size_t)PD2 * PD2P);
    short* w2wb     = allocS((size_t)PD2 * PD2P);
    float* v2b      = allocF((size_t)N1 * 2);
    float* part2    = allocF((size_t)N2 * 16);
    float* router0  = allocF(PD2);
    float* routerp0 = allocF(PD2);
    float* router1  = allocF(PD2);
    float* dscore   = allocF(N1);
    float* rou0     = allocF(N2);
    float* rou1     = allocF(N2);
    float* attr_sum = allocF(N2);
    float* scal     = allocF(8);

    const float INV_TEMP = 0.08838834764831845f; // 1/sqrt(128)

    auto g128 = [&](const short* A, const short* B, const float* bias,
                    float* oF, short* oB, int M, int N, int KP, int ldo, float scale) {
        dim3 g((N + 127) / 128, (M + 127) / 128);
        hipLaunchKernelGGL((gemm_mfma<128, 128>), g, dim3(256), 0, stream,
                           A, B, bias, oF, oB, M, N, KP, ldo, scale);
    };
    auto g64 = [&](const short* A, const short* B, const float* bias,
                   float* oF, short* oB, int M, int N, int KP, int ldo, float scale) {
        dim3 g((N + 63) / 64, (M + 63) / 64);
        hipLaunchKernelGGL((gemm_mfma<64, 64>), g, dim3(256), 0, stream,
                           A, B, bias, oF, oB, M, N, KP, ldo, scale);
    };

    // 1. all conversions + delay/v2 prep, one kernel
    hipLaunchKernelGGL(cvt_all, dim3((C9 + 255) / 256), dim3(256), 0, stream,
                       lm_X, lm_Y, tg_X, aq_w, ak_w, pk_w, pq_w, w1_w, w2_w,
                       lm_delay, tg_delay, g1, g2, g3, al, be, pv_w, pv_b,
                       lmXb, tgXb, aqwb, akwb, pkwb, pqwb, w1wb, w2wb,
                       lmFT, lmFTb, dscore, rou0, rou1, v2b);
    // 2-3. router prep
    hipLaunchKernelGGL(sum_reduce, dim3(1), dim3(256), 0, stream, dscore, scal, N1);
    hipLaunchKernelGGL(router_kernel, dim3(PD2), dim3(256), 0, stream,
                       lmFT, dscore, scal, router0, routerp0);

    // 4-7. attention 1
    g64(lmXb, akwb, ak_b, nullptr, kb_b, N1, DZ, PD, DZ, 1.f);
    g64(tgXb, aqwb, aq_b, nullptr, qb_b, N2, DZ, PD, DZ, INV_TEMP);
    g128(qb_b, kb_b, nullptr, scores, nullptr, N2, N1, DZ, N1, 1.f);
    hipLaunchKernelGGL(softmax_attr, dim3(N2), dim3(256), 0, stream, scores, attr_b, attr_sum);

    // 8-9. propagation 0 (split-K AP + reduce/fixup)
    hipLaunchKernelGGL(ap_gemm, dim3(SPLITS, N2 / 128), dim3(256), 0, stream,
                       attr_b, lmFTb, appart);
    hipLaunchKernelGGL(fix_tgp0, dim3((N2 * PD2P + 255) / 256), dim3(256), 0, stream,
                       appart, tg_X, rou0, router0, attr_sum, tgp0b);

    // 10-11. layer 1
    g64(tgp0b, w1wb, w1_b, tf1, nullptr, N2, PD2, PD2P, PD2, 1.f);
    hipLaunchKernelGGL(router1_kernel, dim3(1), dim3(256), 0, stream,
                       routerp0, w1_w, w1_b, router1);

    // 12-13. propagation 1 + layer 2
    hipLaunchKernelGGL(make_tgp1, dim3((N2 * PD2P + 255) / 256), dim3(256), 0, stream,
                       tf1, rou1, router1, tgp1b);
    g64(tgp1b, w2wb, w2_b, tf2, nullptr, N2, PD2, PD2P, PD2, 1.f);

    // 14. final features -> d_out
    hipLaunchKernelGGL(build_final, dim3((N2 * FDP + 255) / 256), dim3(256), 0, stream,
                       tg_X, tf1, tf2, outF, finalFb);

    // 15-18. attention 2 (fused flash)
    g64(finalFb, pqwb, pq_b, nullptr, q2_b, N2, DZ, FDP, DZ, INV_TEMP);
    g64(lmXb, pkwb, pk_b, nullptr, k2_b, N1, DZ, PD, DZ, 1.f);
    hipLaunchKernelGGL(attn2_flash, dim3(4, N2 / 64), dim3(256), 0, stream,
                       q2_b, k2_b, v2b, part2);
    hipLaunchKernelGGL(attn2_combine, dim3((N2 + 255) / 256), dim3(256), 0, stream,
                       part2, out);
}

// Round 5
// 252.163 us; speedup vs baseline: 4.2029x; 1.3084x over previous
//
#include <hip/hip_runtime.h>

#define N1 4096
#define N2 2048
#define PD 256
#define DZ 128
#define PD2 258
#define PD2P 264     // 258 padded to mult of 8
#define FD 772
#define FDP 776
#define APN 272      // lmFT rows padded to 17*16 (row 258 = ones -> attr_sum)
#define APLD 72      // LDS row stride (shorts) for AP kernel
#define SPLITS 16

typedef short s8v __attribute__((ext_vector_type(8)));   // 8 bf16 (4 VGPRs)
typedef float f32x4 __attribute__((ext_vector_type(4)));

__device__ __forceinline__ short f2b(float f) {
    union { float f; unsigned u; } v; v.f = f;
    unsigned r = v.u + 0x7fffu + ((v.u >> 16) & 1u);
    return (short)(r >> 16);
}
__device__ __forceinline__ float sb2f(short s) {
    union { unsigned u; float f; } v;
    v.u = ((unsigned)(unsigned short)s) << 16;
    return v.f;
}

// ---------------------------------------------------------------- fused prep/convert
constexpr int S0 = N1 * PD;                    // lmXb
constexpr int S1 = S0 + N2 * PD;               // tgXb + outF/finalFb cols 0..255
constexpr int S2 = S1 + DZ * PD;               // aqwb
constexpr int S3 = S2 + 256 * 256;             // wkkb (ak rows 0-127 | pk rows 128-255)
constexpr int S4 = S3 + DZ * FDP;              // pqwb (pad 772->776)
constexpr int S5 = S4 + PD2 * PD2P;            // w1wb
constexpr int S6 = S5 + PD2 * PD2P;            // w2wb
constexpr int S7 = S6 + APN * N1;              // lmFTb [272][4096], row 258 = ones
constexpr int S8 = S7 + N1;                    // delay scores + v2
constexpr int S9 = S8 + 2048 + 8192 + 12288 + 256; // Z zero, finalFb pads, tgp1b pads, biasKK

__global__ __launch_bounds__(256) void cvt_all(
    const float* __restrict__ lmX, const float* __restrict__ lmY,
    const float* __restrict__ tgX,
    const float* __restrict__ aqw, const float* __restrict__ akw,
    const float* __restrict__ pkw, const float* __restrict__ pqw,
    const float* __restrict__ w1w, const float* __restrict__ w2w,
    const float* __restrict__ lmd, const float* __restrict__ tgd,
    const float* __restrict__ g1, const float* __restrict__ g2,
    const float* __restrict__ g3, const float* __restrict__ al,
    const float* __restrict__ be,
    const float* __restrict__ pvw, const float* __restrict__ pvb,
    const float* __restrict__ akb, const float* __restrict__ pkb,
    short* __restrict__ lmXb, short* __restrict__ tgXb,
    short* __restrict__ aqwb, short* __restrict__ wkkb,
    short* __restrict__ pqwb,
    short* __restrict__ w1wb, short* __restrict__ w2wb,
    short* __restrict__ lmFTb,
    float* __restrict__ dscore, float* __restrict__ rou0,
    float* __restrict__ rou1, float* __restrict__ v2b,
    float* __restrict__ Z, short* __restrict__ finalFb,
    short* __restrict__ tgp1b, float* __restrict__ biasKK,
    float* __restrict__ outF)
{
    int i = blockIdx.x * 256 + threadIdx.x;
    if (i < S0) { lmXb[i] = f2b(lmX[i]); return; }
    if (i < S1) { int j = i - S0; int r = j >> 8, c = j & 255;
                  float v = tgX[j];
                  tgXb[j] = f2b(v);
                  outF[(size_t)r * FD + c] = v;
                  finalFb[(size_t)r * FDP + c] = f2b(v); return; }
    if (i < S2) { int j = i - S1; aqwb[j] = f2b(aqw[j]); return; }
    if (i < S3) { int j = i - S2; int r = j >> 8, c = j & 255;
                  wkkb[j] = f2b(r < 128 ? akw[r * 256 + c] : pkw[(r - 128) * 256 + c]);
                  return; }
    if (i < S4) { int j = i - S3; int r = j / FDP, c = j - r * FDP;
                  pqwb[j] = (c < FD) ? f2b(pqw[r * FD + c]) : (short)0; return; }
    if (i < S5) { int j = i - S4; int r = j / PD2P, c = j - r * PD2P;
                  w1wb[j] = (c < PD2) ? f2b(w1w[r * PD2 + c]) : (short)0; return; }
    if (i < S6) { int j = i - S5; int r = j / PD2P, c = j - r * PD2P;
                  w2wb[j] = (c < PD2) ? f2b(w2w[r * PD2 + c]) : (short)0; return; }
    if (i < S7) { int j = i - S6; int c = j >> 12, r = j & (N1 - 1);
                  float v = 0.f;
                  if (c < PD) v = lmX[r * PD + c];
                  else if (c < PD2) v = lmY[r * 2 + (c - PD)];
                  else if (c == PD2) v = 1.0f;          // ones column -> attr_sum
                  lmFTb[j] = f2b(v); return; }
    if (i < S8) { int j = i - S7;   // j in [0,4096)
                  float a = al[0], b = be[0];
                  dscore[j] = __expf(-g1[0] * (a * lmd[j] + b));
                  float y0 = lmY[2 * j], y1 = lmY[2 * j + 1];
                  v2b[2 * j]     = pvw[0] * y0 + pvw[1] * y1 + pvb[0];
                  v2b[2 * j + 1] = pvw[2] * y0 + pvw[3] * y1 + pvb[1];
                  if (j < N2) { float t = a * tgd[j] + b;
                                rou0[j] = __expf(-g2[0] * t);
                                rou1[j] = __expf(-g3[0] * t); }
                  return; }
    if (i < S9) { int j = i - S8;
                  if (j < 2048) { Z[j] = 0.f; return; }
                  j -= 2048;
                  if (j < 8192) { int r = j >> 2, c = FD + (j & 3);
                                  finalFb[(size_t)r * FDP + c] = 0; return; }
                  j -= 8192;
                  if (j < 12288) { int r = j / 6, c = PD2 + (j - r * 6);
                                   tgp1b[(size_t)r * PD2P + c] = 0; return; }
                  j -= 12288;
                  biasKK[j] = (j < 128) ? akb[j] : pkb[j - 128];
                  return; }
}

// router0[c] = mean_i lmF[i][c]; routerp0[c] = (dscore.lmF[:,c] + router0[c]) / (1+sum(dscore)+eps)
__global__ __launch_bounds__(256) void router_kernel(const short* __restrict__ lmFTb,
                                                     const float* __restrict__ dscore,
                                                     float* __restrict__ router0,
                                                     float* __restrict__ routerp0) {
    int c = blockIdx.x;
    const short* rowp = lmFTb + (size_t)c * N1;
    __shared__ float r1[256], r2[256], r3[256];
    int tid = threadIdx.x;
    float s1 = 0.f, s2 = 0.f, s3 = 0.f;
    for (int i = tid; i < N1; i += 256) {
        float v = sb2f(rowp[i]);
        float d = dscore[i];
        s1 += v; s2 += d * v; s3 += d;
    }
    r1[tid] = s1; r2[tid] = s2; r3[tid] = s3; __syncthreads();
    for (int o = 128; o > 0; o >>= 1) {
        if (tid < o) { r1[tid] += r1[tid + o]; r2[tid] += r2[tid + o]; r3[tid] += r3[tid + o]; }
        __syncthreads();
    }
    if (tid == 0) {
        float r0 = r1[0] / (float)N1;
        router0[c] = r0;
        routerp0[c] = (r2[0] + r0) / (1.f + r3[0] + 1e-12f);
    }
}

__global__ __launch_bounds__(256) void router1_kernel(const float* __restrict__ rp0,
                                                      const float* __restrict__ w1w,
                                                      const float* __restrict__ w1b,
                                                      float* __restrict__ router1) {
    for (int c = threadIdx.x; c < PD2; c += 256) {
        float s = w1b[c];
        const float* wr = w1w + (size_t)c * PD2;
        for (int k = 0; k < PD2; ++k) s += rp0[k] * wr[k];
        router1[c] = s;
    }
}

// ---------------------------------------------------------------- projection GEMM (bf16 out)
// out[M,N](bf16, ld ldo) = scale * (A[M,KP] @ B[N,KP]^T + bias[N])
__global__ __launch_bounds__(256) void proj_gemm(
    const short* __restrict__ A, const short* __restrict__ B,
    const float* __restrict__ bias, short* __restrict__ outB,
    int M, int N, int KP, int ldo, float scale)
{
    __shared__ short Als[64][40];
    __shared__ short Bls[64][40];
    const int tid = threadIdx.x;
    const int wave = tid >> 6, lane = tid & 63;
    const int wm = wave >> 1, wn = wave & 1;
    const int lm = lane & 15, lq = lane >> 4;
    const int row0 = blockIdx.y * 64, col0 = blockIdx.x * 64;
    f32x4 acc[2][2];
    const f32x4 zero4 = {0.f, 0.f, 0.f, 0.f};
#pragma unroll
    for (int mt = 0; mt < 2; ++mt)
#pragma unroll
        for (int nt = 0; nt < 2; ++nt) acc[mt][nt] = zero4;
    const s8v zero8 = {0, 0, 0, 0, 0, 0, 0, 0};
    for (int k0 = 0; k0 < KP; k0 += 32) {
        {
            int r = tid >> 2, cg = tid & 3;
            int gk = k0 + cg * 8;
            s8v va = zero8, vb = zero8;
            if (row0 + r < M && gk < KP) va = *(const s8v*)(A + (size_t)(row0 + r) * KP + gk);
            if (col0 + r < N && gk < KP) vb = *(const s8v*)(B + (size_t)(col0 + r) * KP + gk);
            *(s8v*)(&Als[r][cg * 8]) = va;
            *(s8v*)(&Bls[r][cg * 8]) = vb;
        }
        __syncthreads();
        s8v af[2], bf[2];
#pragma unroll
        for (int mt = 0; mt < 2; ++mt)
            af[mt] = *(const s8v*)(&Als[wm * 32 + mt * 16 + lm][lq * 8]);
#pragma unroll
        for (int nt = 0; nt < 2; ++nt)
            bf[nt] = *(const s8v*)(&Bls[wn * 32 + nt * 16 + lm][lq * 8]);
#pragma unroll
        for (int mt = 0; mt < 2; ++mt)
#pragma unroll
            for (int nt = 0; nt < 2; ++nt)
                acc[mt][nt] = __builtin_amdgcn_mfma_f32_16x16x32_bf16(
                    af[mt], bf[nt], acc[mt][nt], 0, 0, 0);
        __syncthreads();
    }
#pragma unroll
    for (int mt = 0; mt < 2; ++mt)
#pragma unroll
        for (int nt = 0; nt < 2; ++nt) {
            int c = col0 + wn * 32 + nt * 16 + lm;
            if (c >= N) continue;
            float bv = bias ? bias[c] : 0.f;
#pragma unroll
            for (int i = 0; i < 4; ++i) {
                int r = row0 + wm * 32 + mt * 16 + lq * 4 + i;
                if (r >= M) continue;
                outB[(size_t)r * ldo + c] = f2b(scale * (acc[mt][nt][i] + bv));
            }
        }
}

// ---------------------------------------------------------------- scores1 + exp fused
// E[r][c] = bf16(exp(q[r].k[c])), Z[r] += row sums (f32, atomics; Z pre-zeroed)
__global__ __launch_bounds__(256) void scores_e(
    const short* __restrict__ Q,       // [2048][128] (already scaled by 1/TEMP)
    const short* __restrict__ Kk,      // kk [4096][256], cols 0..127
    short* __restrict__ E, float* __restrict__ Z)
{
    __shared__ short Als[128][40];
    __shared__ short Bls[128][40];
    const int tid = threadIdx.x;
    const int wave = tid >> 6, lane = tid & 63;
    const int wm = wave >> 1, wn = wave & 1;
    const int lm = lane & 15, lq = lane >> 4;
    const int row0 = blockIdx.y * 128, col0 = blockIdx.x * 128;
    f32x4 acc[4][4];
    const f32x4 zero4 = {0.f, 0.f, 0.f, 0.f};
#pragma unroll
    for (int mt = 0; mt < 4; ++mt)
#pragma unroll
        for (int nt = 0; nt < 4; ++nt) acc[mt][nt] = zero4;
    for (int k0 = 0; k0 < 128; k0 += 32) {
#pragma unroll
        for (int l = 0; l < 2; ++l) {
            int id = l * 256 + tid;
            int r = id >> 2, cg = id & 3;
            int gk = k0 + cg * 8;
            *(s8v*)(&Als[r][cg * 8]) = *(const s8v*)(Q + (size_t)(row0 + r) * DZ + gk);
            *(s8v*)(&Bls[r][cg * 8]) = *(const s8v*)(Kk + (size_t)(col0 + r) * 256 + gk);
        }
        __syncthreads();
        s8v af[4], bf[4];
#pragma unroll
        for (int mt = 0; mt < 4; ++mt)
            af[mt] = *(const s8v*)(&Als[wm * 64 + mt * 16 + lm][lq * 8]);
#pragma unroll
        for (int nt = 0; nt < 4; ++nt)
            bf[nt] = *(const s8v*)(&Bls[wn * 64 + nt * 16 + lm][lq * 8]);
#pragma unroll
        for (int mt = 0; mt < 4; ++mt)
#pragma unroll
            for (int nt = 0; nt < 4; ++nt)
                acc[mt][nt] = __builtin_amdgcn_mfma_f32_16x16x32_bf16(
                    af[mt], bf[nt], acc[mt][nt], 0, 0, 0);
        __syncthreads();
    }
#pragma unroll
    for (int mt = 0; mt < 4; ++mt)
#pragma unroll
        for (int i = 0; i < 4; ++i) {
            int r = row0 + wm * 64 + mt * 16 + lq * 4 + i;
            float rs = 0.f;
#pragma unroll
            for (int nt = 0; nt < 4; ++nt) {
                int c = col0 + wn * 64 + nt * 16 + lm;
                float e = __expf(acc[mt][nt][i]);
                E[(size_t)r * N1 + c] = f2b(e);
                rs += e;
            }
#pragma unroll
            for (int msk = 1; msk < 16; msk <<= 1) rs += __shfl_xor(rs, msk, 64);
            if (lm == 0) atomicAdd(&Z[r], rs);
        }
}

// ---------------------------------------------------------------- AP split-K GEMM
// attr = exp(E*(1/Z)) computed in staging; col 258 output = attr_sum (ones column)
__global__ __launch_bounds__(256) void ap_gemm(const short* __restrict__ E,
                                               const float* __restrict__ Z,
                                               const short* __restrict__ lmFTb,
                                               float* __restrict__ part)
{
    __shared__ short Als[128 * APLD];
    __shared__ short Bls[APN * APLD];
    const int tid = threadIdx.x;
    const int wave = tid >> 6, lane = tid & 63;
    const int lm = lane & 15, lq = lane >> 4;
    const int s = blockIdx.x;           // split 0..15
    const int row0 = blockIdx.y * 128;
    const int kbase = s * (N1 / SPLITS);
    f32x4 acc0[17], acc1[17];
    const f32x4 zero4 = {0.f, 0.f, 0.f, 0.f};
#pragma unroll
    for (int nt = 0; nt < 17; ++nt) { acc0[nt] = zero4; acc1[nt] = zero4; }

    for (int it = 0; it < (N1 / SPLITS) / 64; ++it) {
        int k0 = kbase + it * 64;
#pragma unroll
        for (int l = 0; l < 4; ++l) {          // A: 128 rows x 8 s8v-groups, with exp
            int id = l * 256 + tid;
            int r = id >> 3, g = id & 7;
            s8v ev = *(const s8v*)(E + (size_t)(row0 + r) * N1 + k0 + g * 8);
            float invZ = __builtin_amdgcn_rcpf(Z[row0 + r]);
            s8v av;
#pragma unroll
            for (int j = 0; j < 8; ++j)
                av[j] = f2b(__expf(sb2f(ev[j]) * invZ));
            *(s8v*)(&Als[r * APLD + g * 8]) = av;
        }
#pragma unroll
        for (int l = 0; l < 9; ++l) {          // B: 272 rows x 8 groups = 2176
            int id = l * 256 + tid;
            if (id < APN * 8) {
                int r = id >> 3, g = id & 7;
                *(s8v*)(&Bls[r * APLD + g * 8]) =
                    *(const s8v*)(lmFTb + (size_t)r * N1 + k0 + g * 8);
            }
        }
        __syncthreads();
        s8v a00 = *(const s8v*)(&Als[(wave * 32 + lm) * APLD + lq * 8]);
        s8v a01 = *(const s8v*)(&Als[(wave * 32 + lm) * APLD + 32 + lq * 8]);
        s8v a10 = *(const s8v*)(&Als[(wave * 32 + 16 + lm) * APLD + lq * 8]);
        s8v a11 = *(const s8v*)(&Als[(wave * 32 + 16 + lm) * APLD + 32 + lq * 8]);
#pragma unroll
        for (int nt = 0; nt < 17; ++nt) {
            s8v b0 = *(const s8v*)(&Bls[(nt * 16 + lm) * APLD + lq * 8]);
            s8v b1 = *(const s8v*)(&Bls[(nt * 16 + lm) * APLD + 32 + lq * 8]);
            acc0[nt] = __builtin_amdgcn_mfma_f32_16x16x32_bf16(a00, b0, acc0[nt], 0, 0, 0);
            acc0[nt] = __builtin_amdgcn_mfma_f32_16x16x32_bf16(a01, b1, acc0[nt], 0, 0, 0);
            acc1[nt] = __builtin_amdgcn_mfma_f32_16x16x32_bf16(a10, b0, acc1[nt], 0, 0, 0);
            acc1[nt] = __builtin_amdgcn_mfma_f32_16x16x32_bf16(a11, b1, acc1[nt], 0, 0, 0);
        }
        __syncthreads();
    }
    float* op = part + (size_t)s * N2 * APN;
#pragma unroll
    for (int nt = 0; nt < 17; ++nt) {
        int c = nt * 16 + lm;
#pragma unroll
        for (int i = 0; i < 4; ++i) {
            int r = row0 + wave * 32 + lq * 4 + i;
            op[(size_t)r * APN + c] = acc0[nt][i];
            op[(size_t)(r + 16) * APN + c] = acc1[nt][i];
        }
    }
}

// ---------------------------------------------------------------- tgp0 reduce+fixup
// one block per target row; col 258 of partials = attr_sum
__global__ __launch_bounds__(256) void fix_tgp0(const float* __restrict__ part,
                                                const float* __restrict__ tgX,
                                                const float* __restrict__ rou0,
                                                const float* __restrict__ router0,
                                                short* __restrict__ outb) {
    int r = blockIdx.x;
    int tid = threadIdx.x;
    __shared__ float sAsum;
    float s0 = 0.f, s1 = 0.f;
#pragma unroll
    for (int s = 0; s < SPLITS; ++s)
        s0 += part[((size_t)s * N2 + r) * APN + tid];
    if (tid < 8) {
#pragma unroll
        for (int s = 0; s < SPLITS; ++s)
            s1 += part[((size_t)s * N2 + r) * APN + 256 + tid];
    }
    if (tid == 2) sAsum = s1;   // col 258
    __syncthreads();
    float ro = rou0[r];
    float inv = 1.f / (1.f + sAsum + ro + 1e-12f);
    {   // c = tid (0..255): always < PD
        float v = (s0 + tgX[(size_t)r * PD + tid] + ro * router0[tid]) * inv;
        outb[(size_t)r * PD2P + tid] = f2b(v);
    }
    if (tid < 8) {
        int c = 256 + tid;
        float v = 0.f;
        if (c < PD2) v = (s1 + ro * router0[c]) * inv;   // t0 = 0 for c >= PD
        outb[(size_t)r * PD2P + c] = f2b(v);
    }
}

// ---------------------------------------------------------------- W-layer GEMM (M=2048,N=258,KP=264)
// writes f32 into out columns (ld FD), bf16 into finalFb columns (ld FDP);
// if tgp1b != null also writes tgp1 = (v + rou1*router1)/(1+rou1+eps) as bf16
__global__ __launch_bounds__(256) void w_gemm(
    const short* __restrict__ A, const short* __restrict__ B,
    const float* __restrict__ bias,
    float* __restrict__ outFcol, short* __restrict__ fFbcol,
    const float* __restrict__ rou1, const float* __restrict__ router1,
    short* __restrict__ tgp1b)
{
    __shared__ short Als[64][40];
    __shared__ short Bls[64][40];
    const int tid = threadIdx.x;
    const int wave = tid >> 6, lane = tid & 63;
    const int wm = wave >> 1, wn = wave & 1;
    const int lm = lane & 15, lq = lane >> 4;
    const int row0 = blockIdx.y * 64, col0 = blockIdx.x * 64;
    f32x4 acc[2][2];
    const f32x4 zero4 = {0.f, 0.f, 0.f, 0.f};
#pragma unroll
    for (int mt = 0; mt < 2; ++mt)
#pragma unroll
        for (int nt = 0; nt < 2; ++nt) acc[mt][nt] = zero4;
    const s8v zero8 = {0, 0, 0, 0, 0, 0, 0, 0};
    for (int k0 = 0; k0 < PD2P; k0 += 32) {
        {
            int r = tid >> 2, cg = tid & 3;
            int gk = k0 + cg * 8;
            s8v va = zero8, vb = zero8;
            if (gk < PD2P) {
                va = *(const s8v*)(A + (size_t)(row0 + r) * PD2P + gk);
                if (col0 + r < PD2) vb = *(const s8v*)(B + (size_t)(col0 + r) * PD2P + gk);
            }
            *(s8v*)(&Als[r][cg * 8]) = va;
            *(s8v*)(&Bls[r][cg * 8]) = vb;
        }
        __syncthreads();
        s8v af[2], bf[2];
#pragma unroll
        for (int mt = 0; mt < 2; ++mt)
            af[mt] = *(const s8v*)(&Als[wm * 32 + mt * 16 + lm][lq * 8]);
#pragma unroll
        for (int nt = 0; nt < 2; ++nt)
            bf[nt] = *(const s8v*)(&Bls[wn * 32 + nt * 16 + lm][lq * 8]);
#pragma unroll
        for (int mt = 0; mt < 2; ++mt)
#pragma unroll
            for (int nt = 0; nt < 2; ++nt)
                acc[mt][nt] = __builtin_amdgcn_mfma_f32_16x16x32_bf16(
                    af[mt], bf[nt], acc[mt][nt], 0, 0, 0);
        __syncthreads();
    }
#pragma unroll
    for (int mt = 0; mt < 2; ++mt)
#pragma unroll
        for (int nt = 0; nt < 2; ++nt) {
            int c = col0 + wn * 32 + nt * 16 + lm;
            if (c >= PD2) continue;
            float bv = bias[c];
            float rc = router1 ? router1[c] : 0.f;
#pragma unroll
            for (int i = 0; i < 4; ++i) {
                int r = row0 + wm * 32 + mt * 16 + lq * 4 + i;
                float v = acc[mt][nt][i] + bv;
                outFcol[(size_t)r * FD + c] = v;
                fFbcol[(size_t)r * FDP + c] = f2b(v);
                if (tgp1b) {
                    float ro = rou1[r];
                    float t = (v + ro * rc) / (1.f + ro + 1e-12f);
                    tgp1b[(size_t)r * PD2P + c] = f2b(t);
                }
            }
        }
}

// ---------------------------------------------------------------- fused attention 2 (no-max flash)
// part2[row][chunk] = {z, y0, y1} over chunks of 512 landmarks
__global__ __launch_bounds__(256) void attn2_flash(
    const short* __restrict__ Q,       // [2048][128]
    const short* __restrict__ Kk,      // kk [4096][256], cols 128..255
    const float* __restrict__ V, float* __restrict__ part2)
{
    __shared__ short Qls[64 * 136];
    __shared__ short Kls[64 * 136];
    __shared__ float Vls[128];
    const int tid = threadIdx.x;
    const int wave = tid >> 6, lane = tid & 63;
    const int lm = lane & 15, lq = lane >> 4;
    const int chunk = blockIdx.x;       // 0..7
    const int row0 = blockIdx.y * 64;
#pragma unroll
    for (int l = 0; l < 4; ++l) {
        int id = l * 256 + tid;
        int r = id >> 4, g = id & 15;
        *(s8v*)(&Qls[r * 136 + g * 8]) = *(const s8v*)(Q + (size_t)(row0 + r) * DZ + g * 8);
    }
    __syncthreads();
    s8v af[4];
#pragma unroll
    for (int ks = 0; ks < 4; ++ks)
        af[ks] = *(const s8v*)(&Qls[(wave * 16 + lm) * 136 + ks * 32 + lq * 8]);
    float z[4] = {0.f, 0.f, 0.f, 0.f}, y0[4] = {0.f, 0.f, 0.f, 0.f}, y1[4] = {0.f, 0.f, 0.f, 0.f};

    for (int t = 0; t < 8; ++t) {
        int col0 = chunk * 512 + t * 64;
        __syncthreads();
#pragma unroll
        for (int l = 0; l < 4; ++l) {
            int id = l * 256 + tid;
            int r = id >> 4, g = id & 15;
            *(s8v*)(&Kls[r * 136 + g * 8]) =
                *(const s8v*)(Kk + (size_t)(col0 + r) * 256 + 128 + g * 8);
        }
        if (tid < 128) Vls[tid] = V[col0 * 2 + tid];
        __syncthreads();
        f32x4 acc[4];
        const f32x4 zero4 = {0.f, 0.f, 0.f, 0.f};
#pragma unroll
        for (int nt = 0; nt < 4; ++nt) acc[nt] = zero4;
#pragma unroll
        for (int nt = 0; nt < 4; ++nt)
#pragma unroll
            for (int ks = 0; ks < 4; ++ks) {
                s8v bf = *(const s8v*)(&Kls[(nt * 16 + lm) * 136 + ks * 32 + lq * 8]);
                acc[nt] = __builtin_amdgcn_mfma_f32_16x16x32_bf16(af[ks], bf, acc[nt], 0, 0, 0);
            }
        float v0[4], v1[4];
#pragma unroll
        for (int nt = 0; nt < 4; ++nt) {
            v0[nt] = Vls[(nt * 16 + lm) * 2];
            v1[nt] = Vls[(nt * 16 + lm) * 2 + 1];
        }
#pragma unroll
        for (int i = 0; i < 4; ++i) {
            float e0 = __expf(acc[0][i]), e1 = __expf(acc[1][i]);
            float e2 = __expf(acc[2][i]), e3 = __expf(acc[3][i]);
            float pz = e0 + e1 + e2 + e3;
            float py0 = e0 * v0[0] + e1 * v0[1] + e2 * v0[2] + e3 * v0[3];
            float py1 = e0 * v1[0] + e1 * v1[1] + e2 * v1[2] + e3 * v1[3];
#pragma unroll
            for (int msk = 1; msk < 16; msk <<= 1) {
                pz  += __shfl_xor(pz, msk, 64);
                py0 += __shfl_xor(py0, msk, 64);
                py1 += __shfl_xor(py1, msk, 64);
            }
            z[i] += pz; y0[i] += py0; y1[i] += py1;
        }
    }
    if (lm == 0) {
#pragma unroll
        for (int i = 0; i < 4; ++i) {
            int r = row0 + wave * 16 + lq * 4 + i;
            float* p = part2 + ((size_t)r * 8 + chunk) * 4;
            p[0] = z[i]; p[1] = y0[i]; p[2] = y1[i];
        }
    }
}

__global__ void attn2_combine(const float* __restrict__ part2, float* __restrict__ out) {
    int r = blockIdx.x * blockDim.x + threadIdx.x;
    if (r >= N2) return;
    const float* p = part2 + (size_t)r * 32;
    float Zt = 0.f, Y0 = 0.f, Y1 = 0.f;
#pragma unroll
    for (int c = 0; c < 8; ++c) {
        Zt += p[c * 4]; Y0 += p[c * 4 + 1]; Y1 += p[c * 4 + 2];
    }
    out[2 * r] = Y0 / Zt;
    out[2 * r + 1] = Y1 / Zt;
}

// ---------------------------------------------------------------- launch
extern "C" void kernel_launch(void* const* d_in, const int* in_sizes, int n_in,
                              void* d_out, int out_size, void* d_ws, size_t ws_size,
                              hipStream_t stream) {
    const float* lm_X = (const float*)d_in[0];
    const float* lm_Y = (const float*)d_in[1];
    const float* tg_X = (const float*)d_in[2];
    const float* lm_delay = (const float*)d_in[4];
    const float* tg_delay = (const float*)d_in[5];
    const float* aq_w = (const float*)d_in[6];
    const float* aq_b = (const float*)d_in[7];
    const float* ak_w = (const float*)d_in[8];
    const float* ak_b = (const float*)d_in[9];
    const float* w1_w = (const float*)d_in[10];
    const float* w1_b = (const float*)d_in[11];
    const float* w2_w = (const float*)d_in[12];
    const float* w2_b = (const float*)d_in[13];
    const float* pq_w = (const float*)d_in[14];
    const float* pq_b = (const float*)d_in[15];
    const float* pk_w = (const float*)d_in[16];
    const float* pk_b = (const float*)d_in[17];
    const float* pv_w = (const float*)d_in[18];
    const float* pv_b = (const float*)d_in[19];
    const float* g1 = (const float*)d_in[20];
    const float* g2 = (const float*)d_in[21];
    const float* g3 = (const float*)d_in[22];
    const float* al = (const float*)d_in[23];
    const float* be = (const float*)d_in[24];

    float* out = (float*)d_out;
    float* outF = out + (size_t)N2 * 2;

    char* base = (char*)d_ws;
    size_t off = 0;
    auto allocF = [&](size_t n) -> float* {
        float* p = (float*)(base + off);
        off += (n * 4 + 255) / 256 * 256;
        return p;
    };
    auto allocS = [&](size_t n) -> short* {
        short* p = (short*)(base + off);
        off += (n * 2 + 255) / 256 * 256;
        return p;
    };

    short* E        = allocS((size_t)N2 * N1);        // exp(scores1) bf16
    float* appart   = allocF((size_t)SPLITS * N2 * APN); // 35.7 MB
    short* lmFTb    = allocS((size_t)APN * N1);
    short* lmXb     = allocS((size_t)N1 * PD);
    short* tgXb     = allocS((size_t)N2 * PD);
    short* qb_b     = allocS((size_t)N2 * DZ);
    short* kk       = allocS((size_t)N1 * 256);       // cols 0-127 = k1, 128-255 = k2
    short* q2_b     = allocS((size_t)N2 * DZ);
    short* tgp0b    = allocS((size_t)N2 * PD2P);
    short* tgp1b    = allocS((size_t)N2 * PD2P);
    short* finalFb  = allocS((size_t)N2 * FDP);
    short* aqwb     = allocS((size_t)DZ * PD);
    short* wkkb     = allocS((size_t)256 * 256);
    short* pqwb     = allocS((size_t)DZ * FDP);
    short* w1wb     = allocS((size_t)PD2 * PD2P);
    short* w2wb     = allocS((size_t)PD2 * PD2P);
    float* v2b      = allocF((size_t)N1 * 2);
    float* part2    = allocF((size_t)N2 * 32);
    float* Zbuf     = allocF(N2);
    float* biasKK   = allocF(256);
    float* router0  = allocF(PD2);
    float* routerp0 = allocF(PD2);
    float* router1  = allocF(PD2);
    float* dscore   = allocF(N1);
    float* rou0     = allocF(N2);
    float* rou1     = allocF(N2);

    const float INV_TEMP = 0.08838834764831845f; // 1/sqrt(128)

    // 1. all conversions / copies / zero-fills
    hipLaunchKernelGGL(cvt_all, dim3((S9 + 255) / 256), dim3(256), 0, stream,
                       lm_X, lm_Y, tg_X, aq_w, ak_w, pk_w, pq_w, w1_w, w2_w,
                       lm_delay, tg_delay, g1, g2, g3, al, be, pv_w, pv_b, ak_b, pk_b,
                       lmXb, tgXb, aqwb, wkkb, pqwb, w1wb, w2wb, lmFTb,
                       dscore, rou0, rou1, v2b, Zbuf, finalFb, tgp1b, biasKK, outF);
    // 2-3. router prep (router1 early; independent of attention)
    hipLaunchKernelGGL(router_kernel, dim3(PD2), dim3(256), 0, stream,
                       lmFTb, dscore, router0, routerp0);
    hipLaunchKernelGGL(router1_kernel, dim3(1), dim3(256), 0, stream,
                       routerp0, w1_w, w1_b, router1);

    // 4. kk = lm_X @ [ak|pk]^T + [ak_b|pk_b]   (M=4096,N=256,K=256)
    hipLaunchKernelGGL(proj_gemm, dim3(4, 64), dim3(256), 0, stream,
                       lmXb, wkkb, biasKK, kk, N1, 256, PD, 256, 1.f);
    // 5. qb = (tg_X @ aq^T + aq_b) / TEMP
    hipLaunchKernelGGL(proj_gemm, dim3(2, 32), dim3(256), 0, stream,
                       tgXb, aqwb, aq_b, qb_b, N2, DZ, PD, DZ, INV_TEMP);
    // 6. E = exp(qb @ k1^T), Z row sums
    hipLaunchKernelGGL(scores_e, dim3(32, 16), dim3(256), 0, stream, qb_b, kk, E, Zbuf);
    // 7. AP partials (attr computed in staging; col 258 = attr_sum)
    hipLaunchKernelGGL(ap_gemm, dim3(SPLITS, N2 / 128), dim3(256), 0, stream,
                       E, Zbuf, lmFTb, appart);
    // 8. tgp0
    hipLaunchKernelGGL(fix_tgp0, dim3(N2), dim3(256), 0, stream,
                       appart, tg_X, rou0, router0, tgp0b);
    // 9. tf1 (+ fused tgp1) -> out cols 256..513
    hipLaunchKernelGGL(w_gemm, dim3(5, 32), dim3(256), 0, stream,
                       tgp0b, w1wb, w1_b, outF + 256, finalFb + 256, rou1, router1, tgp1b);
    // 10. tf2 -> out cols 514..771
    hipLaunchKernelGGL(w_gemm, dim3(5, 32), dim3(256), 0, stream,
                       tgp1b, w2wb, w2_b, outF + 514, finalFb + 514,
                       nullptr, nullptr, nullptr);
    // 11. q2 = (final @ pq^T + pq_b) / TEMP
    hipLaunchKernelGGL(proj_gemm, dim3(2, 32), dim3(256), 0, stream,
                       finalFb, pqwb, pq_b, q2_b, N2, DZ, FDP, DZ, INV_TEMP);
    // 12-13. attention 2
    hipLaunchKernelGGL(attn2_flash, dim3(8, N2 / 64), dim3(256), 0, stream,
                       q2_b, kk, v2b, part2);
    hipLaunchKernelGGL(attn2_combine, dim3((N2 + 255) / 256), dim3(256), 0, stream,
                       part2, out);
}